// Round 12
// baseline (403.501 us; speedup 1.0000x reference)
//
#include <hip/hip_runtime.h>
#include <hip/hip_bf16.h>
#include <math.h>

#define V_ 50000
#define OOV_ 100
#define VX_ 50100
#define B_ 256
#define S_ 512
#define TH_ 512
#define SRC_ 512
#define KXH 1664

#define ATT_OFF ((size_t)B_ * VX_)
#define H1_OFF (ATT_OFF + (size_t)B_ * TH_)
#define C1_OFF (H1_OFF + (size_t)B_ * TH_)

typedef float f32x4 __attribute__((ext_vector_type(4)));
typedef short s16x8 __attribute__((ext_vector_type(8)));

__device__ __forceinline__ unsigned short f2bf(float f) {
    unsigned int u = __float_as_uint(f);
    u += 0x7FFFu + ((u >> 16) & 1u);
    return (unsigned short)(u >> 16);
}
// packed f32x2 -> bf16x2 (RNE, same rounding as f2bf); compiler emits cvt_pk
__device__ __forceinline__ unsigned int pk2bf(float x, float y) {
    __hip_bfloat162 h = __float22bfloat162_rn(make_float2(x, y));
    return *reinterpret_cast<unsigned int*>(&h);
}
__device__ __forceinline__ float bf2f(unsigned short u) {
    return __uint_as_float((unsigned int)u << 16);
}
__device__ __forceinline__ float fast_tanh(float x) {
    return 1.0f - 2.0f / (__expf(2.0f * x) + 1.0f);
}
__device__ __forceinline__ float sigm(float x) { return 1.0f / (1.0f + __expf(-x)); }

__device__ __forceinline__ bool get_mask(const void* m, int flag, size_t idx) {
    return flag ? (((const unsigned char*)m)[idx] != 0)
                : (((const int*)m)[idx] != 0);
}

// Builtin MFMA: compiler models MFMA->VALU hazards (inline-asm version corrupted
// accumulators -- round 1->2 lesson).
__device__ __forceinline__ void mfma_acc(f32x4& c, s16x8 a, s16x8 b) {
    c = __builtin_amdgcn_mfma_f32_16x16x32_bf16(a, b, c, 0, 0, 0);
}

// ---- staging helpers -------------------------------------------------------
// LDS tile layout: [rows][128 bytes], swizzle: byte ^= ((row&7)<<4)

__device__ __forceinline__ void stage_bf16(const unsigned short* src, int ld,
                                           int row0, int k0, unsigned char* ldsbase) {
    const int tid = threadIdx.x;
    const int w = tid >> 6, lane = tid & 63;
#pragma unroll
    for (int jj = 0; jj < 2; ++jj) {
        const int qq = w * 2 + jj;               // 0..7, wave-uniform
        const int rowl = qq * 8 + (lane >> 3);
        const int su = (lane & 7) ^ (rowl & 7);  // pre-swizzled global source
        const unsigned short* g = src + (size_t)(row0 + rowl) * ld + k0 + su * 8;
        __builtin_amdgcn_global_load_lds(
            (const __attribute__((address_space(1))) void*)g,
            (__attribute__((address_space(3))) void*)(ldsbase + qq * 1024), 16, 0, 0);
    }
}

// 128-row variant (16 KB tile), same layout/swizzle
__device__ __forceinline__ void stage_bf16_128(const unsigned short* src, int ld,
                                               int k0, unsigned char* ldsbase) {
    const int tid = threadIdx.x;
    const int w = tid >> 6, lane = tid & 63;
#pragma unroll
    for (int jj = 0; jj < 4; ++jj) {
        const int qq = w * 4 + jj;               // 0..15, wave-uniform
        const int rowl = qq * 8 + (lane >> 3);   // 0..127
        const int su = (lane & 7) ^ (rowl & 7);
        const unsigned short* g = src + (size_t)rowl * ld + k0 + su * 8;
        __builtin_amdgcn_global_load_lds(
            (const __attribute__((address_space(1))) void*)g,
            (__attribute__((address_space(3))) void*)(ldsbase + qq * 1024), 16, 0, 0);
    }
}

__device__ __forceinline__ void stage_f32(const float* src, int ld, int row0, int k0,
                                          int rowmax, unsigned char* ldsbase) {
    const int tid = threadIdx.x;
#pragma unroll
    for (int it = 0; it < 4; ++it) {
        const int p = it * 256 + tid;
        const int row = p >> 4;
        const int u4 = p & 15;
        int gr = row0 + row;
        gr = gr > rowmax ? rowmax : gr;
        const float4 v = *(const float4*)(src + (size_t)gr * ld + k0 + u4 * 4);
        *(uint2*)(ldsbase + row * 128 + ((u4 * 8) ^ ((row & 7) << 4))) =
            make_uint2(pk2bf(v.x, v.y), pk2bf(v.z, v.w));
    }
}

__device__ __forceinline__ void compute64(const unsigned char* Ab, const unsigned char* Bb,
                                          f32x4 acc[4]) {
    const int tid = threadIdx.x;
    const int w = tid >> 6, lane = tid & 63, lq = lane >> 4, lr = lane & 15;
#pragma unroll
    for (int ks = 0; ks < 2; ++ks) {
        const int kb = ks * 64 + lq * 16;
        const int ar = w * 16 + lr;
        s16x8 a = *(const s16x8*)(Ab + ar * 128 + (kb ^ ((ar & 7) << 4)));
#pragma unroll
        for (int ns = 0; ns < 4; ++ns) {
            const int br = ns * 16 + lr;
            s16x8 b = *(const s16x8*)(Bb + br * 128 + (kb ^ ((br & 7) << 4)));
            mfma_acc(acc[ns], a, b);
        }
    }
}

// Generic 64x64-tile GEMM core with 1-deep prefetch double-buffer (32 KB LDS).
// One barrier per K-step: barrier drains prev-iter loads into the buffer about
// to be computed; next-iter loads are issued into the other buffer and stay in
// flight across the compute (r5/r8-proven pattern; removing it cost ~10-15 us).
template <bool BF32>
__device__ __forceinline__ void gemm_main(const unsigned short* A, int lda, const void* Bp,
                                          int ldb, int nkc, int kbase, int rowmaxB, int m0,
                                          int n0, unsigned char* smem, f32x4 acc[4]) {
#pragma unroll
    for (int i = 0; i < 4; ++i) acc[i] = f32x4{0.f, 0.f, 0.f, 0.f};
    unsigned char* const A0 = smem;
    unsigned char* const A1 = smem + 8192;
    unsigned char* const B0 = smem + 16384;
    unsigned char* const B1 = smem + 24576;
    stage_bf16(A, lda, m0, kbase, A0);
    if (BF32) stage_f32((const float*)Bp, ldb, n0, kbase, rowmaxB, B0);
    else      stage_bf16((const unsigned short*)Bp, ldb, n0, kbase, B0);
    for (int kc = 0; kc < nkc; ++kc) {
        __syncthreads();   // drains loads for this kc's buffers
        const unsigned char* Ac = (kc & 1) ? A1 : A0;
        const unsigned char* Bc = (kc & 1) ? B1 : B0;
        if (kc + 1 < nkc) {
            const int k0 = kbase + (kc + 1) * 64;
            stage_bf16(A, lda, m0, k0, (kc & 1) ? A0 : A1);
            if (BF32) stage_f32((const float*)Bp, ldb, n0, k0, rowmaxB, (kc & 1) ? B0 : B1);
            else      stage_bf16((const unsigned short*)Bp, ldb, n0, k0, (kc & 1) ? B0 : B1);
        }
        compute64(Ac, Bc, acc);
    }
}

// ---- kernels ---------------------------------------------------------------

// Fused prelude: all mutually-independent setup work in ONE launch.
__global__ __launch_bounds__(256) void k_pre(const float* enc, const int* stok, const int* ptok,
                                             float* cs_sum, int* cs_cnt, unsigned short* ebf,
                                             int do_cvt, float* logit, float* rowsum,
                                             const void* maskp, int* flag, float* out,
                                             const float* W_ih, const float* W_hh,
                                             const float* W_copy, const float* W_attn,
                                             unsigned short* Wg, unsigned short* Wcb,
                                             unsigned short* wab, float* gates) {
    const int bid = blockIdx.x, tid = threadIdx.x;
    if (bid < 1024) {
        __shared__ float comb[512];
        __shared__ int cc[2];
        const int b = bid >> 2, chunk = bid & 3;
        const int h = tid >> 7, d0 = (tid & 127) * 4;
        const int prev = ptok[b];
        const float* base = enc + ((size_t)b * S_ + chunk * 128) * SRC_;
        const int* st = stok + b * S_ + chunk * 128;
        unsigned short* eb = ebf + ((size_t)b * S_ + chunk * 128) * SRC_;
        float a0 = 0.f, a1 = 0.f, a2 = 0.f, a3 = 0.f;
        int cnt = 0;
        for (int s2 = 0; s2 < 64; ++s2) {
            const int s = s2 * 2 + h;
            const float4 v = *(const float4*)(base + (size_t)s * SRC_ + d0);
            if (st[s] != prev) { a0 += v.x; a1 += v.y; a2 += v.z; a3 += v.w; ++cnt; }
            if (do_cvt) {
                *(uint2*)(eb + (size_t)s * SRC_ + d0) =
                    make_uint2(pk2bf(v.x, v.y), pk2bf(v.z, v.w));
            }
        }
        if (h == 0) {
            comb[d0] = a0; comb[d0 + 1] = a1; comb[d0 + 2] = a2; comb[d0 + 3] = a3;
            if (tid == 0) cc[0] = cnt;
        }
        __syncthreads();
        if (h == 1) {
            comb[d0] += a0; comb[d0 + 1] += a1; comb[d0 + 2] += a2; comb[d0 + 3] += a3;
            if (tid == 128) cc[1] = cnt;
        }
        __syncthreads();
        cs_sum[(size_t)bid * SRC_ + tid] = comb[tid];
        cs_sum[(size_t)bid * SRC_ + 256 + tid] = comb[256 + tid];
        if (tid == 0) cs_cnt[bid] = cc[0] + cc[1];
    } else if (bid < 1536) {
        logit[(bid - 1024) * 256 + tid] = 0.f;
    } else if (bid == 1536) {
        rowsum[tid] = (float)OOV_;
    } else if (bid == 1537) {
        __shared__ int sfl;
        if (tid == 0) sfl = 0;
        __syncthreads();
        const uint4* m4 = (const uint4*)maskp;
        unsigned int ev = 0;
        for (int i = tid; i < (B_ * S_) / 16; i += 256) {
            const uint4 u = m4[i];
            ev |= (u.x | u.y | u.z | u.w) & 0xFFFFFF00u;
        }
        if (ev) atomicOr(&sfl, 1);
        __syncthreads();
        if (tid == 0) *flag = sfl;   // 1 => bool(1B) layout, 0 => int32 layout
    } else if (bid < 1638) {
        const int p = (bid - 1538) * 256 + tid;
        if (p < B_ * OOV_) {
            const int b = p / OOV_, j = p - b * OOV_;
            out[(size_t)b * VX_ + V_ + j] = 1.0f;   // exp(0) base for OOV columns
        }
    } else if (bid < 2150) {
        const int NWG = 2048 * KXH;
        const int NTOT4 = (NWG + 512 * 512) / 4;
        for (int i4 = (bid - 1638) * 256 + tid; i4 < NTOT4; i4 += 512 * 256) {
            const int e = i4 * 4;
            float4 v;
            unsigned short* dst;
            if (e < NWG) {
                const int r = e / KXH, c = e - r * KXH;
                v = (c < 1152) ? *(const float4*)(W_ih + (size_t)r * 1152 + c)
                               : *(const float4*)(W_hh + (size_t)r * 512 + (c - 1152));
                dst = Wg + e;
            } else {
                v = *(const float4*)(W_copy + (e - NWG));
                dst = Wcb + (e - NWG);
            }
            *(uint2*)dst = make_uint2(pk2bf(v.x, v.y), pk2bf(v.z, v.w));
        }
    } else if (bid < 2662) {
        ((float4*)gates)[(bid - 2150) * 256 + tid] = make_float4(0.f, 0.f, 0.f, 0.f);
    } else {
        // W_attn f32 -> bf16 (512 KB), blocks [2662, 2726)
        for (int i4 = (bid - 2662) * 256 + tid; i4 < 65536; i4 += 64 * 256) {
            const float4 v = *(const float4*)(W_attn + (size_t)i4 * 4);
            *(uint2*)(wab + (size_t)i4 * 4) = make_uint2(pk2bf(v.x, v.y), pk2bf(v.z, v.w));
        }
    }
}

__global__ __launch_bounds__(256) void k_cs_final(const float* cs_sum, const int* cs_cnt,
                                                  const float* embedding, const int* ptok,
                                                  const float* pcs, const float* h0,
                                                  unsigned short* xh) {
    const int b = blockIdx.x, tid = threadIdx.x;
    const int cnt = cs_cnt[b * 4] + cs_cnt[b * 4 + 1] + cs_cnt[b * 4 + 2] + cs_cnt[b * 4 + 3];
    const float inv = 1.f / (float)cnt;
    unsigned short* row = xh + (size_t)b * KXH;
    for (int d = tid; d < 512; d += 256) {
        float s = cs_sum[(size_t)(b * 4 + 0) * SRC_ + d] + cs_sum[(size_t)(b * 4 + 1) * SRC_ + d] +
                  cs_sum[(size_t)(b * 4 + 2) * SRC_ + d] + cs_sum[(size_t)(b * 4 + 3) * SRC_ + d];
        row[640 + d] = f2bf(s * inv);              // copy_state
        row[128 + d] = f2bf(pcs[b * 512 + d]);     // prev_context_state
        row[1152 + d] = f2bf(h0[b * 512 + d]);     // h0 (for W_hh part)
    }
    if (tid < 128) {
        int tk = ptok[b];
        if (tk >= V_) tk = 1;  // UNK
        row[tid] = f2bf(embedding[(size_t)tk * 128 + tid]);
    }
}

// split-K=2: each half atomicAdds into zero-initialized gates. Exactly 2
// commutative float adds per element onto exact 0 -> deterministic.
__global__ __launch_bounds__(256) void k_gates(const unsigned short* xh, const unsigned short* Wg,
                                               float* gates) {
    __shared__ __align__(16) unsigned char smem[32768];
    f32x4 acc[4];
    const int m0 = blockIdx.x * 64, n0 = blockIdx.y * 64;
    const int kb = blockIdx.z ? 832 : 0;
    gemm_main<false>(xh, KXH, Wg, KXH, 13, kb, 2047, m0, n0, smem, acc);
    const int tid = threadIdx.x, w = tid >> 6, lane = tid & 63, lq = lane >> 4, lr = lane & 15;
#pragma unroll
    for (int ns = 0; ns < 4; ++ns) {
        const int n = n0 + ns * 16 + lr;
#pragma unroll
        for (int r = 0; r < 4; ++r) {
            const int m = m0 + w * 16 + lq * 4 + r;
            atomicAdd(&gates[(size_t)m * 2048 + n], acc[ns][r]);
        }
    }
}

__global__ __launch_bounds__(256) void k_lstm(const float* gates, const float* b_ih,
                                              const float* b_hh, const float* c0, float* out,
                                              unsigned short* h1b) {
    const int idx = blockIdx.x * 256 + threadIdx.x;  // 0..131071
    const int b = idx >> 9, h = idx & 511;
    const float gi = gates[(size_t)b * 2048 + h] + b_ih[h] + b_hh[h];
    const float gf = gates[(size_t)b * 2048 + 512 + h] + b_ih[512 + h] + b_hh[512 + h];
    const float gg = gates[(size_t)b * 2048 + 1024 + h] + b_ih[1024 + h] + b_hh[1024 + h];
    const float go = gates[(size_t)b * 2048 + 1536 + h] + b_ih[1536 + h] + b_hh[1536 + h];
    const float c1 = sigm(gf) * c0[idx] + sigm(gi) * fast_tanh(gg);
    const float h1 = sigm(go) * fast_tanh(c1);
    out[H1_OFF + idx] = h1;
    out[C1_OFF + idx] = c1;
    h1b[idx] = f2bf(h1);
}

// Fused q + attention: block computes its own q-row (h1b @ wab^T, both bf16 --
// the same quantization the old MFMA k_q used) then runs the 16-wave
// register-resident online softmax with a single LDS merge.
__global__ __launch_bounds__(1024) void k_attn3(const float* enc, const unsigned short* ebf,
                                                const int use_ebf, const unsigned short* wab,
                                                const void* maskp, const int* flagp,
                                                const unsigned short* h1b, unsigned short* ch) {
    __shared__ float plds[16][512];
    __shared__ float mdl[16][2];
    __shared__ float qlds[512];
    __shared__ __align__(16) unsigned short h1lds[512];
    const int b = blockIdx.x;
    const int tid = threadIdx.x, w = tid >> 6, lane = tid & 63;
    const int flag = *flagp;
    if (tid < 64)
        *(uint4*)&h1lds[tid * 8] = *(const uint4*)&h1b[(size_t)b * 512 + tid * 8];
    __syncthreads();
    {   // q[n] = sum_k h1[k] * W_attn[n][k]; n = tid>>1, k-half = tid&1
        const int n = tid >> 1, kh = tid & 1;
        const unsigned short* wr = wab + (size_t)n * 512 + kh * 256;
        const unsigned short* hr = h1lds + kh * 256;
        float s = 0.f;
        for (int j = 0; j < 256; j += 8) {
            const uint4 uw = *(const uint4*)(wr + j);
            const uint4 uh = *(const uint4*)(hr + j);
            const unsigned int wv[4] = {uw.x, uw.y, uw.z, uw.w};
            const unsigned int hv[4] = {uh.x, uh.y, uh.z, uh.w};
#pragma unroll
            for (int q2 = 0; q2 < 4; ++q2) {
                s += __uint_as_float(wv[q2] << 16) * __uint_as_float(hv[q2] << 16);
                s += __uint_as_float(wv[q2] & 0xffff0000u) *
                     __uint_as_float(hv[q2] & 0xffff0000u);
            }
        }
        s += __shfl_xor(s, 1);
        if (kh == 0) qlds[n] = s;
    }
    __syncthreads();
    float q0[8];
    {
        const float4 t0 = *(const float4*)&qlds[lane * 8];
        const float4 t1 = *(const float4*)&qlds[lane * 8 + 4];
        q0[0] = t0.x; q0[1] = t0.y; q0[2] = t0.z; q0[3] = t0.w;
        q0[4] = t1.x; q0[5] = t1.y; q0[6] = t1.z; q0[7] = t1.w;
    }
    float M = -INFINITY, den = 0.f;
    float cv[8] = {0.f, 0.f, 0.f, 0.f, 0.f, 0.f, 0.f, 0.f};
    const int s0 = w * 32;
    for (int i = 0; i < 32; ++i) {
        const int s = s0 + i;
        if (get_mask(maskp, flag, (size_t)b * S_ + s)) continue;  // wave-uniform
        float v[8];
        if (use_ebf) {
            const uint4 u = *(const uint4*)(ebf + ((size_t)b * S_ + s) * 512 + lane * 8);
            v[0] = __uint_as_float(u.x << 16);
            v[1] = __uint_as_float(u.x & 0xffff0000u);
            v[2] = __uint_as_float(u.y << 16);
            v[3] = __uint_as_float(u.y & 0xffff0000u);
            v[4] = __uint_as_float(u.z << 16);
            v[5] = __uint_as_float(u.z & 0xffff0000u);
            v[6] = __uint_as_float(u.w << 16);
            v[7] = __uint_as_float(u.w & 0xffff0000u);
        } else {
            const float4 t0 = *(const float4*)(enc + ((size_t)b * S_ + s) * 512 + lane * 8);
            const float4 t1 = *(const float4*)(enc + ((size_t)b * S_ + s) * 512 + lane * 8 + 4);
            v[0] = t0.x; v[1] = t0.y; v[2] = t0.z; v[3] = t0.w;
            v[4] = t1.x; v[5] = t1.y; v[6] = t1.z; v[7] = t1.w;
        }
        float a = 0.f;
#pragma unroll
        for (int j = 0; j < 8; ++j) a += q0[j] * v[j];
        a += __shfl_xor(a, 1);
        a += __shfl_xor(a, 2);
        a += __shfl_xor(a, 4);
        a += __shfl_xor(a, 8);
        a += __shfl_xor(a, 16);
        a += __shfl_xor(a, 32);
        const float nM = fmaxf(M, a);
        const float sc = __expf(M - nM);   // M=-inf -> 0
        const float p = __expf(a - nM);
        den = den * sc + p;
#pragma unroll
        for (int j = 0; j < 8; ++j) cv[j] = cv[j] * sc + p * v[j];
        M = nM;
    }
    if (lane == 0) { mdl[w][0] = M; mdl[w][1] = den; }
    *(float4*)&plds[w][lane * 8] = make_float4(cv[0], cv[1], cv[2], cv[3]);
    *(float4*)&plds[w][lane * 8 + 4] = make_float4(cv[4], cv[5], cv[6], cv[7]);
    __syncthreads();
    if (tid < 512) {
        float Mg = -INFINITY;
#pragma unroll
        for (int j = 0; j < 16; ++j) Mg = fmaxf(Mg, mdl[j][0]);
        float deng = 0.f, c = 0.f;
#pragma unroll
        for (int j = 0; j < 16; ++j) {
            const float sc = __expf(mdl[j][0] - Mg);  // -inf -> 0
            deng += mdl[j][1] * sc;
            c += plds[j][tid] * sc;
        }
        ch[(size_t)b * 1024 + tid] = f2bf(c / deng);
    } else {
        ch[(size_t)b * 1024 + tid] = h1b[(size_t)b * 512 + (tid - 512)];
    }
}

__global__ __launch_bounds__(256) void k_attnout(const unsigned short* ch, const float* W_out,
                                                 const float* b_out, float* out,
                                                 unsigned short* aob) {
    __shared__ __align__(16) unsigned char smem[32768];
    f32x4 acc[4];
    const int m0 = blockIdx.x * 64, n0 = blockIdx.y * 64;
    gemm_main<true>(ch, 1024, W_out, 1024, 16, 0, 511, m0, n0, smem, acc);
    const int tid = threadIdx.x, w = tid >> 6, lane = tid & 63, lq = lane >> 4, lr = lane & 15;
#pragma unroll
    for (int ns = 0; ns < 4; ++ns) {
        const int n = n0 + ns * 16 + lr;
        const float bb = b_out[n];
#pragma unroll
        for (int r = 0; r < 4; ++r) {
            const int m = m0 + w * 16 + lq * 4 + r;
            const float t = fast_tanh(acc[ns][r] + bb);
            out[ATT_OFF + (size_t)m * 512 + n] = t;
            aob[(size_t)m * 512 + n] = f2bf(t);
        }
    }
}

// Fused tail (r8 structure): copyseq blocks [0,4096), XCD-swizzled, 1-deep
// global_load_lds double-buffer on BOTH operands (64 KB, 0 bank conflicts);
// gen blocks [4096,7224), XCD-swizzled, prefetched gemm_main.
__global__ __launch_bounds__(256) void k_tail(const unsigned short* ebf,
                                              const unsigned short* Wcb, const float* ao,
                                              const unsigned short* aob, const float* W_gen,
                                              const void* maskp, const int* flagp, float* out,
                                              float* logit, float* rowsum) {
    __shared__ __align__(16) unsigned char smem[65536];
    const int tid = threadIdx.x;
    const int w = tid >> 6, lane = tid & 63;
    const int lq = lane >> 4, lr = lane & 15;

    if (blockIdx.x < 4096) {
        // ---- copy_seq GEMM ----
        const int d = blockIdx.x;                  // 0..4095
        const int l = (d & 7) * 512 + (d >> 3);    // bijective (4096 = 8*512)
        const int n0 = (l & 3) * 128;
        const int mt = l >> 2;
        const int m0 = mt * 128;
        const int b = mt >> 2;
        if (get_mask(maskp, *flagp, (size_t)b * S_ + (m0 & 511))) return;  // tile masked
        unsigned char* const A0 = smem;
        unsigned char* const A1 = smem + 16384;
        unsigned char* const B0 = smem + 32768;
        unsigned char* const B1 = smem + 49152;
        const int wm = w >> 1, wn = w & 1;
        const unsigned short* Asrc = ebf + (size_t)m0 * 512;
        const unsigned short* Bsrc = Wcb + (size_t)n0 * 512;

        f32x4 acc[4][4];
#pragma unroll
        for (int mi = 0; mi < 4; ++mi)
#pragma unroll
            for (int ni = 0; ni < 4; ++ni) acc[mi][ni] = f32x4{0.f, 0.f, 0.f, 0.f};

        stage_bf16_128(Asrc, 512, 0, A0);
        stage_bf16_128(Bsrc, 512, 0, B0);

        for (int kc = 0; kc < 8; ++kc) {
            __syncthreads();   // drains loads issued for this kc (vmcnt0 at barrier)
            const unsigned char* Ac = (kc & 1) ? A1 : A0;
            const unsigned char* Bc = (kc & 1) ? B1 : B0;
            if (kc < 7) {      // issue next-kc loads; they drain at NEXT barrier
                stage_bf16_128(Asrc, 512, (kc + 1) * 64, (kc & 1) ? A0 : A1);
                stage_bf16_128(Bsrc, 512, (kc + 1) * 64, (kc & 1) ? B0 : B1);
            }
#pragma unroll
            for (int ks = 0; ks < 2; ++ks) {
                const int kb = ks * 64 + lq * 16;
                s16x8 afr[4], bfr[4];
#pragma unroll
                for (int mi = 0; mi < 4; ++mi) {
                    const int ar = wm * 64 + mi * 16 + lr;
                    afr[mi] = *(const s16x8*)(Ac + ar * 128 + (kb ^ ((ar & 7) << 4)));
                }
#pragma unroll
                for (int ni = 0; ni < 4; ++ni) {
                    const int br = wn * 64 + ni * 16 + lr;
                    bfr[ni] = *(const s16x8*)(Bc + br * 128 + (kb ^ ((br & 7) << 4)));
                }
#pragma unroll
                for (int mi = 0; mi < 4; ++mi)
#pragma unroll
                    for (int ni = 0; ni < 4; ++ni) mfma_acc(acc[mi][ni], afr[mi], bfr[ni]);
            }
        }

        // epilogue: logit[s] += sum over this wave's 64 n-cols of tanh(P)*ao
        float aow[4];
#pragma unroll
        for (int ni = 0; ni < 4; ++ni) aow[ni] = ao[b * 512 + n0 + wn * 64 + ni * 16 + lr];
#pragma unroll
        for (int mi = 0; mi < 4; ++mi) {
#pragma unroll
            for (int r = 0; r < 4; ++r) {
                float p = 0.f;
#pragma unroll
                for (int ni = 0; ni < 4; ++ni) p += fast_tanh(acc[mi][ni][r]) * aow[ni];
                p += __shfl_xor(p, 1, 16);
                p += __shfl_xor(p, 2, 16);
                p += __shfl_xor(p, 4, 16);
                p += __shfl_xor(p, 8, 16);
                if (lr == 0)
                    atomicAdd(&logit[(size_t)m0 + wm * 64 + mi * 16 + lq * 4 + r], p);
            }
        }
    } else {
        // ---- gen GEMM + exp + rowsum ----
        const int d = blockIdx.x - 4096;           // 0..3127
        const int l = (d & 7) * 391 + (d >> 3);    // bijective (3128 = 8*391)
        const int m0 = (l & 3) * 64;
        const int n0 = (l >> 2) * 64;
        f32x4 acc[4];
        gemm_main<true>(aob, 512, W_gen, 512, 8, 0, V_ - 1, m0, n0, smem, acc);
        float rp[4] = {0.f, 0.f, 0.f, 0.f};
#pragma unroll
        for (int ns = 0; ns < 4; ++ns) {
            const int n = n0 + ns * 16 + lr;
            if (n < V_) {
#pragma unroll
                for (int r = 0; r < 4; ++r) {
                    const float v = __expf(acc[ns][r]);
                    out[(size_t)(m0 + w * 16 + lq * 4 + r) * VX_ + n] = v;
                    rp[r] += v;
                }
            }
        }
#pragma unroll
        for (int r = 0; r < 4; ++r) {
            rp[r] += __shfl_xor(rp[r], 1, 16);
            rp[r] += __shfl_xor(rp[r], 2, 16);
            rp[r] += __shfl_xor(rp[r], 4, 16);
            rp[r] += __shfl_xor(rp[r], 8, 16);
        }
        if (lr == 0) {
#pragma unroll
            for (int r = 0; r < 4; ++r) atomicAdd(&rowsum[m0 + w * 16 + lq * 4 + r], rp[r]);
        }
    }
}

// Fallback (ws too small for ebf): f32 enc, single-buffer, reg-staged A convert.
__global__ __launch_bounds__(256) void k_copyseq(const float* enc, const unsigned short* Wcb,
                                                 const float* ao, const void* maskp,
                                                 const int* flagp, float* logit) {
    const int m0 = blockIdx.x * 128;
    const int n0 = blockIdx.y * 128;
    const int b = blockIdx.x >> 2;
    if (get_mask(maskp, *flagp, (size_t)b * S_ + (m0 & 511))) return;
    __shared__ __align__(16) unsigned char smem[32768];
    unsigned char* const A0 = smem;
    unsigned char* const B0 = smem + 16384;
    const int tid = threadIdx.x;
    const int w = tid >> 6, lane = tid & 63;
    const int wm = w >> 1, wn = w & 1, lq = lane >> 4, lr = lane & 15;
    const float* Asrc = enc + (size_t)m0 * 512;

    f32x4 acc[4][4];
#pragma unroll
    for (int mi = 0; mi < 4; ++mi)
#pragma unroll
        for (int ni = 0; ni < 4; ++ni) acc[mi][ni] = f32x4{0.f, 0.f, 0.f, 0.f};

    const int arow_t = tid >> 3, au_t = tid & 7;
    for (int kc = 0; kc < 8; ++kc) {
        __syncthreads();
        const int k0 = kc * 64;
#pragma unroll
        for (int it = 0; it < 4; ++it) {
            const int row = arow_t + it * 32;
            const float* g = Asrc + (size_t)row * 512 + k0 + au_t * 8;
            const float4 v0 = *(const float4*)g;
            const float4 v1 = *(const float4*)(g + 4);
            uint4 pk;
            pk.x = pk2bf(v0.x, v0.y);
            pk.y = pk2bf(v0.z, v0.w);
            pk.z = pk2bf(v1.x, v1.y);
            pk.w = pk2bf(v1.z, v1.w);
            *(uint4*)(A0 + row * 128 + ((au_t * 16) ^ ((row & 7) << 4))) = pk;
        }
        stage_bf16_128(Wcb + (size_t)n0 * 512, 512, k0, B0);
        __syncthreads();
#pragma unroll
        for (int ks = 0; ks < 2; ++ks) {
            const int kb = ks * 64 + lq * 16;
            s16x8 afr[4], bfr[4];
#pragma unroll
            for (int mi = 0; mi < 4; ++mi) {
                const int ar = wm * 64 + mi * 16 + lr;
                afr[mi] = *(const s16x8*)(A0 + ar * 128 + (kb ^ ((ar & 7) << 4)));
            }
#pragma unroll
            for (int ni = 0; ni < 4; ++ni) {
                const int br = wn * 64 + ni * 16 + lr;
                bfr[ni] = *(const s16x8*)(B0 + br * 128 + (kb ^ ((br & 7) << 4)));
            }
#pragma unroll
            for (int mi = 0; mi < 4; ++mi)
#pragma unroll
                for (int ni = 0; ni < 4; ++ni) mfma_acc(acc[mi][ni], afr[mi], bfr[ni]);
        }
    }

    float aow[4];
#pragma unroll
    for (int ni = 0; ni < 4; ++ni) aow[ni] = ao[b * 512 + n0 + wn * 64 + ni * 16 + lr];
#pragma unroll
    for (int mi = 0; mi < 4; ++mi) {
#pragma unroll
        for (int r = 0; r < 4; ++r) {
            float p = 0.f;
#pragma unroll
            for (int ni = 0; ni < 4; ++ni) p += fast_tanh(acc[mi][ni][r]) * aow[ni];
            p += __shfl_xor(p, 1, 16);
            p += __shfl_xor(p, 2, 16);
            p += __shfl_xor(p, 4, 16);
            p += __shfl_xor(p, 8, 16);
            if (lr == 0)
                atomicAdd(&logit[(size_t)m0 + wm * 64 + mi * 16 + lq * 4 + r], p);
        }
    }
}

// Fallback gen (paired with k_copyseq when no ebf)
__global__ __launch_bounds__(256) void k_gen(const unsigned short* aob, const float* W_gen,
                                             float* out, float* rowsum) {
    __shared__ __align__(16) unsigned char smem[32768];
    f32x4 acc[4];
    const int d = blockIdx.x;
    const int l = (d & 7) * 391 + (d >> 3);
    const int m0 = (l & 3) * 64;
    const int n0 = (l >> 2) * 64;
    gemm_main<true>(aob, 512, W_gen, 512, 8, 0, V_ - 1, m0, n0, smem, acc);
    const int tid = threadIdx.x, w = tid >> 6, lane = tid & 63, lq = lane >> 4, lr = lane & 15;
    float rp[4] = {0.f, 0.f, 0.f, 0.f};
#pragma unroll
    for (int ns = 0; ns < 4; ++ns) {
        const int n = n0 + ns * 16 + lr;
        if (n < V_) {
#pragma unroll
            for (int r = 0; r < 4; ++r) {
                const float v = __expf(acc[ns][r]);
                out[(size_t)(m0 + w * 16 + lq * 4 + r) * VX_ + n] = v;
                rp[r] += v;
            }
        }
    }
#pragma unroll
    for (int r = 0; r < 4; ++r) {
        rp[r] += __shfl_xor(rp[r], 1, 16);
        rp[r] += __shfl_xor(rp[r], 2, 16);
        rp[r] += __shfl_xor(rp[r], 4, 16);
        rp[r] += __shfl_xor(rp[r], 8, 16);
    }
    if (lr == 0) {
#pragma unroll
        for (int r = 0; r < 4; ++r) atomicAdd(&rowsum[m0 + w * 16 + lq * 4 + r], rp[r]);
    }
}

__global__ __launch_bounds__(256) void k_scatter(const float* logit, const int* stok,
                                                 const void* maskp, const int* flagp,
                                                 float* out, float* rowsum) {
    const int idx = blockIdx.x * 256 + threadIdx.x;
    const int b = idx >> 9;
    const int flag = *flagp;
    float v = 0.f;
    if (!get_mask(maskp, flag, idx)) {
        v = __expf(logit[idx]);
        atomicAdd(&out[(size_t)b * VX_ + stok[idx]], v);
    }
    float s = v;
#pragma unroll
    for (int o = 1; o < 64; o <<= 1) s += __shfl_xor(s, o, 64);
    if ((threadIdx.x & 63) == 0) atomicAdd(&rowsum[b], s);
}

// float4 log pass: VX_ = 50100 = 4*12525; each row 16B-aligned (200400 % 16 == 0)
__global__ __launch_bounds__(256) void k_final(float* out, const float* rowsum) {
    const int b = blockIdx.y;
    const float ls = __logf(rowsum[b]);
    const int p = blockIdx.x * 256 + threadIdx.x;
    if (p < 12525) {
        float4* o4 = (float4*)(out + (size_t)b * VX_) + p;
        float4 v = *o4;
        v.x = __logf(v.x) - ls;
        v.y = __logf(v.y) - ls;
        v.z = __logf(v.z) - ls;
        v.w = __logf(v.w) - ls;
        *o4 = v;
    }
}

// ---- host ------------------------------------------------------------------

extern "C" void kernel_launch(void* const* d_in, const int* in_sizes, int n_in, void* d_out,
                              int out_size, void* d_ws, size_t ws_size, hipStream_t stream) {
    const float* embedding = (const float*)d_in[0];
    const float* W_ih = (const float*)d_in[1];
    const float* W_hh = (const float*)d_in[2];
    const float* b_ih = (const float*)d_in[3];
    const float* b_hh = (const float*)d_in[4];
    const float* W_attn = (const float*)d_in[5];
    const float* W_out = (const float*)d_in[6];
    const float* b_out = (const float*)d_in[7];
    const float* W_copy = (const float*)d_in[8];
    // d_in[9] = W_incopy: provably dead in the reference (tanh(0)=0 on unmatched,
    // matched positions masked to -inf => softmax is uniform over unmatched).
    const float* W_gen = (const float*)d_in[10];
    const float* enc = (const float*)d_in[11];
    const float* pcs = (const float*)d_in[12];
    const float* h0 = (const float*)d_in[13];
    const float* c0 = (const float*)d_in[14];
    const int* ptok = (const int*)d_in[15];
    const int* stok = (const int*)d_in[16];
    const void* maskp = d_in[17];
    float* out = (float*)d_out;

    char* ws = (char*)d_ws;
    size_t off = 0;
    auto alloc = [&](size_t bytes) {
        size_t o = off;
        off += (bytes + 255) & ~(size_t)255;
        return o;
    };
    int* flag = (int*)(ws + alloc(4));
    float* rowsum = (float*)(ws + alloc(B_ * 4));
    float* cs_sum = (float*)(ws + alloc((size_t)1024 * SRC_ * 4));
    int* cs_cnt = (int*)(ws + alloc(1024 * 4));
    unsigned short* xh = (unsigned short*)(ws + alloc((size_t)B_ * KXH * 2));
    unsigned short* Wg = (unsigned short*)(ws + alloc((size_t)2048 * KXH * 2));
    unsigned short* Wcb = (unsigned short*)(ws + alloc((size_t)512 * 512 * 2));
    unsigned short* wab = (unsigned short*)(ws + alloc((size_t)512 * 512 * 2));
    float* gates = (float*)(ws + alloc((size_t)B_ * 2048 * 4));
    unsigned short* h1b = (unsigned short*)(ws + alloc((size_t)B_ * 512 * 2));
    unsigned short* ch = (unsigned short*)(ws + alloc((size_t)B_ * 1024 * 2));
    unsigned short* aob = (unsigned short*)(ws + alloc((size_t)B_ * 512 * 2));
    float* logit = (float*)(ws + alloc((size_t)B_ * S_ * 4));
    const size_t ebf_bytes = (size_t)B_ * S_ * SRC_ * 2;  // 134 MB
    const int use_ebf = (off + ebf_bytes <= ws_size) ? 1 : 0;
    unsigned short* ebf = (unsigned short*)(ws + off);
    (void)n_in; (void)in_sizes; (void)out_size;

    hipLaunchKernelGGL(k_pre, dim3(2726), dim3(256), 0, stream, enc, stok, ptok, cs_sum, cs_cnt,
                       ebf, use_ebf, logit, rowsum, maskp, flag, out, W_ih, W_hh, W_copy,
                       W_attn, Wg, Wcb, wab, gates);
    hipLaunchKernelGGL(k_cs_final, dim3(256), dim3(256), 0, stream, cs_sum, cs_cnt, embedding,
                       ptok, pcs, h0, xh);
    hipLaunchKernelGGL(k_gates, dim3(4, 32, 2), dim3(256), 0, stream, xh, Wg, gates);
    hipLaunchKernelGGL(k_lstm, dim3(512), dim3(256), 0, stream, gates, b_ih, b_hh, c0, out, h1b);
    hipLaunchKernelGGL(k_attn3, dim3(256), dim3(1024), 0, stream, enc, ebf, use_ebf, wab,
                       maskp, flag, h1b, ch);
    hipLaunchKernelGGL(k_attnout, dim3(4, 8), dim3(256), 0, stream, ch, W_out, b_out, out, aob);
    if (use_ebf) {
        hipLaunchKernelGGL(k_tail, dim3(7224), dim3(256), 0, stream, ebf, Wcb, out + ATT_OFF,
                           aob, W_gen, maskp, flag, out, logit, rowsum);
    } else {
        hipLaunchKernelGGL(k_gen, dim3(3128), dim3(256), 0, stream, aob, W_gen, out, rowsum);
        hipLaunchKernelGGL(k_copyseq, dim3(1024, 4), dim3(256), 0, stream, enc, Wcb,
                           out + ATT_OFF, maskp, flag, logit);
    }
    hipLaunchKernelGGL(k_scatter, dim3(512), dim3(256), 0, stream, logit, stok, maskp, flag,
                       out, rowsum);
    hipLaunchKernelGGL(k_final, dim3(49, 256), dim3(256), 0, stream, out, rowsum);
}

// Round 13
// 393.838 us; speedup vs baseline: 1.0245x; 1.0245x over previous
//
#include <hip/hip_runtime.h>
#include <hip/hip_bf16.h>
#include <math.h>

#define V_ 50000
#define OOV_ 100
#define VX_ 50100
#define B_ 256
#define S_ 512
#define TH_ 512
#define SRC_ 512
#define KXH 1664

#define ATT_OFF ((size_t)B_ * VX_)
#define H1_OFF (ATT_OFF + (size_t)B_ * TH_)
#define C1_OFF (H1_OFF + (size_t)B_ * TH_)

typedef float f32x4 __attribute__((ext_vector_type(4)));
typedef short s16x8 __attribute__((ext_vector_type(8)));

__device__ __forceinline__ unsigned short f2bf(float f) {
    unsigned int u = __float_as_uint(f);
    u += 0x7FFFu + ((u >> 16) & 1u);
    return (unsigned short)(u >> 16);
}
// packed f32x2 -> bf16x2 (RNE, same rounding as f2bf); compiler emits cvt_pk
__device__ __forceinline__ unsigned int pk2bf(float x, float y) {
    __hip_bfloat162 h = __float22bfloat162_rn(make_float2(x, y));
    return *reinterpret_cast<unsigned int*>(&h);
}
__device__ __forceinline__ float fast_tanh(float x) {
    return 1.0f - 2.0f / (__expf(2.0f * x) + 1.0f);
}
__device__ __forceinline__ float sigm(float x) { return 1.0f / (1.0f + __expf(-x)); }

__device__ __forceinline__ bool get_mask(const void* m, int flag, size_t idx) {
    return flag ? (((const unsigned char*)m)[idx] != 0)
                : (((const int*)m)[idx] != 0);
}

// Builtin MFMA: compiler models MFMA->VALU hazards (inline-asm version corrupted
// accumulators -- round 1->2 lesson).
__device__ __forceinline__ void mfma_acc(f32x4& c, s16x8 a, s16x8 b) {
    c = __builtin_amdgcn_mfma_f32_16x16x32_bf16(a, b, c, 0, 0, 0);
}

// ---- staging helpers -------------------------------------------------------
// LDS tile layout: [rows][128 bytes], swizzle: byte ^= ((row&7)<<4)

__device__ __forceinline__ void stage_bf16(const unsigned short* src, int ld,
                                           int row0, int k0, unsigned char* ldsbase) {
    const int tid = threadIdx.x;
    const int w = tid >> 6, lane = tid & 63;
#pragma unroll
    for (int jj = 0; jj < 2; ++jj) {
        const int qq = w * 2 + jj;               // 0..7, wave-uniform
        const int rowl = qq * 8 + (lane >> 3);
        const int su = (lane & 7) ^ (rowl & 7);  // pre-swizzled global source
        const unsigned short* g = src + (size_t)(row0 + rowl) * ld + k0 + su * 8;
        __builtin_amdgcn_global_load_lds(
            (const __attribute__((address_space(1))) void*)g,
            (__attribute__((address_space(3))) void*)(ldsbase + qq * 1024), 16, 0, 0);
    }
}

// 128-row variant (16 KB tile), same layout/swizzle
__device__ __forceinline__ void stage_bf16_128(const unsigned short* src, int ld,
                                               int k0, unsigned char* ldsbase) {
    const int tid = threadIdx.x;
    const int w = tid >> 6, lane = tid & 63;
#pragma unroll
    for (int jj = 0; jj < 4; ++jj) {
        const int qq = w * 4 + jj;               // 0..15, wave-uniform
        const int rowl = qq * 8 + (lane >> 3);   // 0..127
        const int su = (lane & 7) ^ (rowl & 7);
        const unsigned short* g = src + (size_t)rowl * ld + k0 + su * 8;
        __builtin_amdgcn_global_load_lds(
            (const __attribute__((address_space(1))) void*)g,
            (__attribute__((address_space(3))) void*)(ldsbase + qq * 1024), 16, 0, 0);
    }
}

__device__ __forceinline__ void stage_f32(const float* src, int ld, int row0, int k0,
                                          int rowmax, unsigned char* ldsbase) {
    const int tid = threadIdx.x;
#pragma unroll
    for (int it = 0; it < 4; ++it) {
        const int p = it * 256 + tid;
        const int row = p >> 4;
        const int u4 = p & 15;
        int gr = row0 + row;
        gr = gr > rowmax ? rowmax : gr;
        const float4 v = *(const float4*)(src + (size_t)gr * ld + k0 + u4 * 4);
        *(uint2*)(ldsbase + row * 128 + ((u4 * 8) ^ ((row & 7) << 4))) =
            make_uint2(pk2bf(v.x, v.y), pk2bf(v.z, v.w));
    }
}

__device__ __forceinline__ void compute64(const unsigned char* Ab, const unsigned char* Bb,
                                          f32x4 acc[4]) {
    const int tid = threadIdx.x;
    const int w = tid >> 6, lane = tid & 63, lq = lane >> 4, lr = lane & 15;
#pragma unroll
    for (int ks = 0; ks < 2; ++ks) {
        const int kb = ks * 64 + lq * 16;
        const int ar = w * 16 + lr;
        s16x8 a = *(const s16x8*)(Ab + ar * 128 + (kb ^ ((ar & 7) << 4)));
#pragma unroll
        for (int ns = 0; ns < 4; ++ns) {
            const int br = ns * 16 + lr;
            s16x8 b = *(const s16x8*)(Bb + br * 128 + (kb ^ ((br & 7) << 4)));
            mfma_acc(acc[ns], a, b);
        }
    }
}

// Generic 64x64-tile GEMM core with 1-deep prefetch double-buffer (32 KB LDS).
// One barrier per K-step: barrier drains prev-iter loads into the buffer about
// to be computed; next-iter loads are issued into the other buffer and stay in
// flight across the compute (r5/r8-proven pattern; removing it cost ~10-15 us).
template <bool BF32>
__device__ __forceinline__ void gemm_main(const unsigned short* A, int lda, const void* Bp,
                                          int ldb, int nkc, int kbase, int rowmaxB, int m0,
                                          int n0, unsigned char* smem, f32x4 acc[4]) {
#pragma unroll
    for (int i = 0; i < 4; ++i) acc[i] = f32x4{0.f, 0.f, 0.f, 0.f};
    unsigned char* const A0 = smem;
    unsigned char* const A1 = smem + 8192;
    unsigned char* const B0 = smem + 16384;
    unsigned char* const B1 = smem + 24576;
    stage_bf16(A, lda, m0, kbase, A0);
    if (BF32) stage_f32((const float*)Bp, ldb, n0, kbase, rowmaxB, B0);
    else      stage_bf16((const unsigned short*)Bp, ldb, n0, kbase, B0);
    for (int kc = 0; kc < nkc; ++kc) {
        __syncthreads();   // drains loads for this kc's buffers
        const unsigned char* Ac = (kc & 1) ? A1 : A0;
        const unsigned char* Bc = (kc & 1) ? B1 : B0;
        if (kc + 1 < nkc) {
            const int k0 = kbase + (kc + 1) * 64;
            stage_bf16(A, lda, m0, k0, (kc & 1) ? A0 : A1);
            if (BF32) stage_f32((const float*)Bp, ldb, n0, k0, rowmaxB, (kc & 1) ? B0 : B1);
            else      stage_bf16((const unsigned short*)Bp, ldb, n0, k0, (kc & 1) ? B0 : B1);
        }
        compute64(Ac, Bc, acc);
    }
}

// ---- kernels ---------------------------------------------------------------

// Fused prelude: all mutually-independent setup work in ONE launch.
__global__ __launch_bounds__(256) void k_pre(const float* enc, const int* stok, const int* ptok,
                                             float* cs_sum, int* cs_cnt, unsigned short* ebf,
                                             int do_cvt, float* logit, float* rowsum,
                                             const void* maskp, int* flag, float* out,
                                             const float* W_ih, const float* W_hh,
                                             const float* W_copy, unsigned short* Wg,
                                             unsigned short* Wcb, float* gates) {
    const int bid = blockIdx.x, tid = threadIdx.x;
    if (bid < 1024) {
        __shared__ float comb[512];
        __shared__ int cc[2];
        const int b = bid >> 2, chunk = bid & 3;
        const int h = tid >> 7, d0 = (tid & 127) * 4;
        const int prev = ptok[b];
        const float* base = enc + ((size_t)b * S_ + chunk * 128) * SRC_;
        const int* st = stok + b * S_ + chunk * 128;
        unsigned short* eb = ebf + ((size_t)b * S_ + chunk * 128) * SRC_;
        float a0 = 0.f, a1 = 0.f, a2 = 0.f, a3 = 0.f;
        int cnt = 0;
        for (int s2 = 0; s2 < 64; ++s2) {
            const int s = s2 * 2 + h;
            const float4 v = *(const float4*)(base + (size_t)s * SRC_ + d0);
            if (st[s] != prev) { a0 += v.x; a1 += v.y; a2 += v.z; a3 += v.w; ++cnt; }
            if (do_cvt) {
                *(uint2*)(eb + (size_t)s * SRC_ + d0) =
                    make_uint2(pk2bf(v.x, v.y), pk2bf(v.z, v.w));
            }
        }
        if (h == 0) {
            comb[d0] = a0; comb[d0 + 1] = a1; comb[d0 + 2] = a2; comb[d0 + 3] = a3;
            if (tid == 0) cc[0] = cnt;
        }
        __syncthreads();
        if (h == 1) {
            comb[d0] += a0; comb[d0 + 1] += a1; comb[d0 + 2] += a2; comb[d0 + 3] += a3;
            if (tid == 128) cc[1] = cnt;
        }
        __syncthreads();
        cs_sum[(size_t)bid * SRC_ + tid] = comb[tid];
        cs_sum[(size_t)bid * SRC_ + 256 + tid] = comb[256 + tid];
        if (tid == 0) cs_cnt[bid] = cc[0] + cc[1];
    } else if (bid < 1536) {
        logit[(bid - 1024) * 256 + tid] = 0.f;
    } else if (bid == 1536) {
        rowsum[tid] = (float)OOV_;
    } else if (bid == 1537) {
        __shared__ int sfl;
        if (tid == 0) sfl = 0;
        __syncthreads();
        const uint4* m4 = (const uint4*)maskp;
        unsigned int ev = 0;
        for (int i = tid; i < (B_ * S_) / 16; i += 256) {
            const uint4 u = m4[i];
            ev |= (u.x | u.y | u.z | u.w) & 0xFFFFFF00u;
        }
        if (ev) atomicOr(&sfl, 1);
        __syncthreads();
        if (tid == 0) *flag = sfl;   // 1 => bool(1B) layout, 0 => int32 layout
    } else if (bid < 1638) {
        const int p = (bid - 1538) * 256 + tid;
        if (p < B_ * OOV_) {
            const int b = p / OOV_, j = p - b * OOV_;
            out[(size_t)b * VX_ + V_ + j] = 1.0f;   // exp(0) base for OOV columns
        }
    } else if (bid < 2150) {
        const int NWG = 2048 * KXH;
        const int NTOT4 = (NWG + 512 * 512) / 4;
        for (int i4 = (bid - 1638) * 256 + tid; i4 < NTOT4; i4 += 512 * 256) {
            const int e = i4 * 4;
            float4 v;
            unsigned short* dst;
            if (e < NWG) {
                const int r = e / KXH, c = e - r * KXH;
                v = (c < 1152) ? *(const float4*)(W_ih + (size_t)r * 1152 + c)
                               : *(const float4*)(W_hh + (size_t)r * 512 + (c - 1152));
                dst = Wg + e;
            } else {
                v = *(const float4*)(W_copy + (e - NWG));
                dst = Wcb + (e - NWG);
            }
            *(uint2*)dst = make_uint2(pk2bf(v.x, v.y), pk2bf(v.z, v.w));
        }
    } else {
        ((float4*)gates)[(bid - 2150) * 256 + tid] = make_float4(0.f, 0.f, 0.f, 0.f);
    }
}

__global__ __launch_bounds__(256) void k_cs_final(const float* cs_sum, const int* cs_cnt,
                                                  const float* embedding, const int* ptok,
                                                  const float* pcs, const float* h0,
                                                  unsigned short* xh) {
    const int b = blockIdx.x, tid = threadIdx.x;
    const int cnt = cs_cnt[b * 4] + cs_cnt[b * 4 + 1] + cs_cnt[b * 4 + 2] + cs_cnt[b * 4 + 3];
    const float inv = 1.f / (float)cnt;
    unsigned short* row = xh + (size_t)b * KXH;
    for (int d = tid; d < 512; d += 256) {
        float s = cs_sum[(size_t)(b * 4 + 0) * SRC_ + d] + cs_sum[(size_t)(b * 4 + 1) * SRC_ + d] +
                  cs_sum[(size_t)(b * 4 + 2) * SRC_ + d] + cs_sum[(size_t)(b * 4 + 3) * SRC_ + d];
        row[640 + d] = f2bf(s * inv);              // copy_state
        row[128 + d] = f2bf(pcs[b * 512 + d]);     // prev_context_state
        row[1152 + d] = f2bf(h0[b * 512 + d]);     // h0 (for W_hh part)
    }
    if (tid < 128) {
        int tk = ptok[b];
        if (tk >= V_) tk = 1;  // UNK
        row[tid] = f2bf(embedding[(size_t)tk * 128 + tid]);
    }
}

// split-K=2: each half atomicAdds into zero-initialized gates. Exactly 2
// commutative float adds per element onto exact 0 -> deterministic.
__global__ __launch_bounds__(256) void k_gates(const unsigned short* xh, const unsigned short* Wg,
                                               float* gates) {
    __shared__ __align__(16) unsigned char smem[32768];
    f32x4 acc[4];
    const int m0 = blockIdx.x * 64, n0 = blockIdx.y * 64;
    const int kb = blockIdx.z ? 832 : 0;
    gemm_main<false>(xh, KXH, Wg, KXH, 13, kb, 2047, m0, n0, smem, acc);
    const int tid = threadIdx.x, w = tid >> 6, lane = tid & 63, lq = lane >> 4, lr = lane & 15;
#pragma unroll
    for (int ns = 0; ns < 4; ++ns) {
        const int n = n0 + ns * 16 + lr;
#pragma unroll
        for (int r = 0; r < 4; ++r) {
            const int m = m0 + w * 16 + lq * 4 + r;
            atomicAdd(&gates[(size_t)m * 2048 + n], acc[ns][r]);
        }
    }
}

__global__ __launch_bounds__(256) void k_lstm(const float* gates, const float* b_ih,
                                              const float* b_hh, const float* c0, float* out,
                                              unsigned short* h1b) {
    const int idx = blockIdx.x * 256 + threadIdx.x;  // 0..131071
    const int b = idx >> 9, h = idx & 511;
    const float gi = gates[(size_t)b * 2048 + h] + b_ih[h] + b_hh[h];
    const float gf = gates[(size_t)b * 2048 + 512 + h] + b_ih[512 + h] + b_hh[512 + h];
    const float gg = gates[(size_t)b * 2048 + 1024 + h] + b_ih[1024 + h] + b_hh[1024 + h];
    const float go = gates[(size_t)b * 2048 + 1536 + h] + b_ih[1536 + h] + b_hh[1536 + h];
    const float c1 = sigm(gf) * c0[idx] + sigm(gi) * fast_tanh(gg);
    const float h1 = sigm(go) * fast_tanh(c1);
    out[H1_OFF + idx] = h1;
    out[C1_OFF + idx] = c1;
    h1b[idx] = f2bf(h1);
}

__global__ __launch_bounds__(256) void k_q(const unsigned short* h1b, const float* W_attn,
                                           float* qbuf) {
    __shared__ __align__(16) unsigned char smem[32768];
    f32x4 acc[4];
    const int m0 = blockIdx.x * 64, n0 = blockIdx.y * 64;
    gemm_main<true>(h1b, 512, W_attn, 512, 8, 0, 511, m0, n0, smem, acc);
    const int tid = threadIdx.x, w = tid >> 6, lane = tid & 63, lq = lane >> 4, lr = lane & 15;
#pragma unroll
    for (int ns = 0; ns < 4; ++ns) {
        const int n = n0 + ns * 16 + lr;
#pragma unroll
        for (int r = 0; r < 4; ++r)
            qbuf[(size_t)(m0 + w * 16 + lq * 4 + r) * 512 + n] = acc[ns][r];
    }
}

// Fused attention: 16 waves/block, wave w owns s-rows [w*32, w*32+32) with
// register-resident online softmax; single LDS merge replaces the parts/md
// global round-trip and the separate merge kernel.
__global__ __launch_bounds__(1024) void k_attn3(const float* enc, const unsigned short* ebf,
                                                const int use_ebf, const float* qv,
                                                const void* maskp, const int* flagp,
                                                const unsigned short* h1b, unsigned short* ch) {
    __shared__ float plds[16][512];
    __shared__ float mdl[16][2];
    const int b = blockIdx.x;
    const int tid = threadIdx.x, w = tid >> 6, lane = tid & 63;
    const int flag = *flagp;
    float q0[8];
    {
        const float4 t0 = *(const float4*)(qv + b * 512 + lane * 8);
        const float4 t1 = *(const float4*)(qv + b * 512 + lane * 8 + 4);
        q0[0] = t0.x; q0[1] = t0.y; q0[2] = t0.z; q0[3] = t0.w;
        q0[4] = t1.x; q0[5] = t1.y; q0[6] = t1.z; q0[7] = t1.w;
    }
    float M = -INFINITY, den = 0.f;
    float cv[8] = {0.f, 0.f, 0.f, 0.f, 0.f, 0.f, 0.f, 0.f};
    const int s0 = w * 32;
    for (int i = 0; i < 32; ++i) {
        const int s = s0 + i;
        if (get_mask(maskp, flag, (size_t)b * S_ + s)) continue;  // wave-uniform
        float v[8];
        if (use_ebf) {
            const uint4 u = *(const uint4*)(ebf + ((size_t)b * S_ + s) * 512 + lane * 8);
            v[0] = __uint_as_float(u.x << 16);
            v[1] = __uint_as_float(u.x & 0xffff0000u);
            v[2] = __uint_as_float(u.y << 16);
            v[3] = __uint_as_float(u.y & 0xffff0000u);
            v[4] = __uint_as_float(u.z << 16);
            v[5] = __uint_as_float(u.z & 0xffff0000u);
            v[6] = __uint_as_float(u.w << 16);
            v[7] = __uint_as_float(u.w & 0xffff0000u);
        } else {
            const float4 t0 = *(const float4*)(enc + ((size_t)b * S_ + s) * 512 + lane * 8);
            const float4 t1 = *(const float4*)(enc + ((size_t)b * S_ + s) * 512 + lane * 8 + 4);
            v[0] = t0.x; v[1] = t0.y; v[2] = t0.z; v[3] = t0.w;
            v[4] = t1.x; v[5] = t1.y; v[6] = t1.z; v[7] = t1.w;
        }
        float a = 0.f;
#pragma unroll
        for (int j = 0; j < 8; ++j) a += q0[j] * v[j];
        a += __shfl_xor(a, 1);
        a += __shfl_xor(a, 2);
        a += __shfl_xor(a, 4);
        a += __shfl_xor(a, 8);
        a += __shfl_xor(a, 16);
        a += __shfl_xor(a, 32);
        const float nM = fmaxf(M, a);
        const float sc = __expf(M - nM);   // M=-inf -> 0
        const float p = __expf(a - nM);
        den = den * sc + p;
#pragma unroll
        for (int j = 0; j < 8; ++j) cv[j] = cv[j] * sc + p * v[j];
        M = nM;
    }
    if (lane == 0) { mdl[w][0] = M; mdl[w][1] = den; }
    *(float4*)&plds[w][lane * 8] = make_float4(cv[0], cv[1], cv[2], cv[3]);
    *(float4*)&plds[w][lane * 8 + 4] = make_float4(cv[4], cv[5], cv[6], cv[7]);
    __syncthreads();
    if (tid < 512) {
        float Mg = -INFINITY;
#pragma unroll
        for (int j = 0; j < 16; ++j) Mg = fmaxf(Mg, mdl[j][0]);
        float deng = 0.f, c = 0.f;
#pragma unroll
        for (int j = 0; j < 16; ++j) {
            const float sc = __expf(mdl[j][0] - Mg);  // -inf -> 0
            deng += mdl[j][1] * sc;
            c += plds[j][tid] * sc;
        }
        ch[(size_t)b * 1024 + tid] = f2bf(c / deng);
    } else {
        ch[(size_t)b * 1024 + tid] = h1b[b * 512 + (tid - 512)];
    }
}

__global__ __launch_bounds__(256) void k_attnout(const unsigned short* ch, const float* W_out,
                                                 const float* b_out, float* out,
                                                 unsigned short* aob) {
    __shared__ __align__(16) unsigned char smem[32768];
    f32x4 acc[4];
    const int m0 = blockIdx.x * 64, n0 = blockIdx.y * 64;
    gemm_main<true>(ch, 1024, W_out, 1024, 16, 0, 511, m0, n0, smem, acc);
    const int tid = threadIdx.x, w = tid >> 6, lane = tid & 63, lq = lane >> 4, lr = lane & 15;
#pragma unroll
    for (int ns = 0; ns < 4; ++ns) {
        const int n = n0 + ns * 16 + lr;
        const float bb = b_out[n];
#pragma unroll
        for (int r = 0; r < 4; ++r) {
            const int m = m0 + w * 16 + lq * 4 + r;
            const float t = fast_tanh(acc[ns][r] + bb);
            out[ATT_OFF + (size_t)m * 512 + n] = t;
            aob[(size_t)m * 512 + n] = f2bf(t);
        }
    }
}

// Fused tail (r8 structure): copyseq blocks [0,4096), XCD-swizzled, 1-deep
// global_load_lds double-buffer on BOTH operands (64 KB, 0 bank conflicts);
// gen blocks [4096,7224), XCD-swizzled, prefetched gemm_main.
__global__ __launch_bounds__(256) void k_tail(const unsigned short* ebf,
                                              const unsigned short* Wcb, const float* ao,
                                              const unsigned short* aob, const float* W_gen,
                                              const void* maskp, const int* flagp, float* out,
                                              float* logit, float* rowsum) {
    __shared__ __align__(16) unsigned char smem[65536];
    const int tid = threadIdx.x;
    const int w = tid >> 6, lane = tid & 63;
    const int lq = lane >> 4, lr = lane & 15;

    if (blockIdx.x < 4096) {
        // ---- copy_seq GEMM ----
        const int d = blockIdx.x;                  // 0..4095
        const int l = (d & 7) * 512 + (d >> 3);    // bijective (4096 = 8*512)
        const int n0 = (l & 3) * 128;
        const int mt = l >> 2;
        const int m0 = mt * 128;
        const int b = mt >> 2;
        if (get_mask(maskp, *flagp, (size_t)b * S_ + (m0 & 511))) return;  // tile masked
        unsigned char* const A0 = smem;
        unsigned char* const A1 = smem + 16384;
        unsigned char* const B0 = smem + 32768;
        unsigned char* const B1 = smem + 49152;
        const int wm = w >> 1, wn = w & 1;
        const unsigned short* Asrc = ebf + (size_t)m0 * 512;
        const unsigned short* Bsrc = Wcb + (size_t)n0 * 512;

        f32x4 acc[4][4];
#pragma unroll
        for (int mi = 0; mi < 4; ++mi)
#pragma unroll
            for (int ni = 0; ni < 4; ++ni) acc[mi][ni] = f32x4{0.f, 0.f, 0.f, 0.f};

        stage_bf16_128(Asrc, 512, 0, A0);
        stage_bf16_128(Bsrc, 512, 0, B0);

        for (int kc = 0; kc < 8; ++kc) {
            __syncthreads();   // drains loads issued for this kc (vmcnt0 at barrier)
            const unsigned char* Ac = (kc & 1) ? A1 : A0;
            const unsigned char* Bc = (kc & 1) ? B1 : B0;
            if (kc < 7) {      // issue next-kc loads; they drain at NEXT barrier
                stage_bf16_128(Asrc, 512, (kc + 1) * 64, (kc & 1) ? A0 : A1);
                stage_bf16_128(Bsrc, 512, (kc + 1) * 64, (kc & 1) ? B0 : B1);
            }
#pragma unroll
            for (int ks = 0; ks < 2; ++ks) {
                const int kb = ks * 64 + lq * 16;
                s16x8 afr[4], bfr[4];
#pragma unroll
                for (int mi = 0; mi < 4; ++mi) {
                    const int ar = wm * 64 + mi * 16 + lr;
                    afr[mi] = *(const s16x8*)(Ac + ar * 128 + (kb ^ ((ar & 7) << 4)));
                }
#pragma unroll
                for (int ni = 0; ni < 4; ++ni) {
                    const int br = wn * 64 + ni * 16 + lr;
                    bfr[ni] = *(const s16x8*)(Bc + br * 128 + (kb ^ ((br & 7) << 4)));
                }
#pragma unroll
                for (int mi = 0; mi < 4; ++mi)
#pragma unroll
                    for (int ni = 0; ni < 4; ++ni) mfma_acc(acc[mi][ni], afr[mi], bfr[ni]);
            }
        }

        // epilogue: logit[s] += sum over this wave's 64 n-cols of tanh(P)*ao
        float aow[4];
#pragma unroll
        for (int ni = 0; ni < 4; ++ni) aow[ni] = ao[b * 512 + n0 + wn * 64 + ni * 16 + lr];
#pragma unroll
        for (int mi = 0; mi < 4; ++mi) {
#pragma unroll
            for (int r = 0; r < 4; ++r) {
                float p = 0.f;
#pragma unroll
                for (int ni = 0; ni < 4; ++ni) p += fast_tanh(acc[mi][ni][r]) * aow[ni];
                p += __shfl_xor(p, 1, 16);
                p += __shfl_xor(p, 2, 16);
                p += __shfl_xor(p, 4, 16);
                p += __shfl_xor(p, 8, 16);
                if (lr == 0)
                    atomicAdd(&logit[(size_t)m0 + wm * 64 + mi * 16 + lq * 4 + r], p);
            }
        }
    } else {
        // ---- gen GEMM + exp + rowsum ----
        const int d = blockIdx.x - 4096;           // 0..3127
        const int l = (d & 7) * 391 + (d >> 3);    // bijective (3128 = 8*391)
        const int m0 = (l & 3) * 64;
        const int n0 = (l >> 2) * 64;
        f32x4 acc[4];
        gemm_main<true>(aob, 512, W_gen, 512, 8, 0, V_ - 1, m0, n0, smem, acc);
        float rp[4] = {0.f, 0.f, 0.f, 0.f};
#pragma unroll
        for (int ns = 0; ns < 4; ++ns) {
            const int n = n0 + ns * 16 + lr;
            if (n < V_) {
#pragma unroll
                for (int r = 0; r < 4; ++r) {
                    const float v = __expf(acc[ns][r]);
                    out[(size_t)(m0 + w * 16 + lq * 4 + r) * VX_ + n] = v;
                    rp[r] += v;
                }
            }
        }
#pragma unroll
        for (int r = 0; r < 4; ++r) {
            rp[r] += __shfl_xor(rp[r], 1, 16);
            rp[r] += __shfl_xor(rp[r], 2, 16);
            rp[r] += __shfl_xor(rp[r], 4, 16);
            rp[r] += __shfl_xor(rp[r], 8, 16);
        }
        if (lr == 0) {
#pragma unroll
            for (int r = 0; r < 4; ++r) atomicAdd(&rowsum[m0 + w * 16 + lq * 4 + r], rp[r]);
        }
    }
}

// Fallback (ws too small for ebf): f32 enc, single-buffer, reg-staged A convert.
__global__ __launch_bounds__(256) void k_copyseq(const float* enc, const unsigned short* Wcb,
                                                 const float* ao, const void* maskp,
                                                 const int* flagp, float* logit) {
    const int m0 = blockIdx.x * 128;
    const int n0 = blockIdx.y * 128;
    const int b = blockIdx.x >> 2;
    if (get_mask(maskp, *flagp, (size_t)b * S_ + (m0 & 511))) return;
    __shared__ __align__(16) unsigned char smem[32768];
    unsigned char* const A0 = smem;
    unsigned char* const B0 = smem + 16384;
    const int tid = threadIdx.x;
    const int w = tid >> 6, lane = tid & 63;
    const int wm = w >> 1, wn = w & 1, lq = lane >> 4, lr = lane & 15;
    const float* Asrc = enc + (size_t)m0 * 512;

    f32x4 acc[4][4];
#pragma unroll
    for (int mi = 0; mi < 4; ++mi)
#pragma unroll
        for (int ni = 0; ni < 4; ++ni) acc[mi][ni] = f32x4{0.f, 0.f, 0.f, 0.f};

    const int arow_t = tid >> 3, au_t = tid & 7;
    for (int kc = 0; kc < 8; ++kc) {
        __syncthreads();
        const int k0 = kc * 64;
#pragma unroll
        for (int it = 0; it < 4; ++it) {
            const int row = arow_t + it * 32;
            const float* g = Asrc + (size_t)row * 512 + k0 + au_t * 8;
            const float4 v0 = *(const float4*)g;
            const float4 v1 = *(const float4*)(g + 4);
            uint4 pk;
            pk.x = pk2bf(v0.x, v0.y);
            pk.y = pk2bf(v0.z, v0.w);
            pk.z = pk2bf(v1.x, v1.y);
            pk.w = pk2bf(v1.z, v1.w);
            *(uint4*)(A0 + row * 128 + ((au_t * 16) ^ ((row & 7) << 4))) = pk;
        }
        stage_bf16_128(Wcb + (size_t)n0 * 512, 512, k0, B0);
        __syncthreads();
#pragma unroll
        for (int ks = 0; ks < 2; ++ks) {
            const int kb = ks * 64 + lq * 16;
            s16x8 afr[4], bfr[4];
#pragma unroll
            for (int mi = 0; mi < 4; ++mi) {
                const int ar = wm * 64 + mi * 16 + lr;
                afr[mi] = *(const s16x8*)(A0 + ar * 128 + (kb ^ ((ar & 7) << 4)));
            }
#pragma unroll
            for (int ni = 0; ni < 4; ++ni) {
                const int br = wn * 64 + ni * 16 + lr;
                bfr[ni] = *(const s16x8*)(B0 + br * 128 + (kb ^ ((br & 7) << 4)));
            }
#pragma unroll
            for (int mi = 0; mi < 4; ++mi)
#pragma unroll
                for (int ni = 0; ni < 4; ++ni) mfma_acc(acc[mi][ni], afr[mi], bfr[ni]);
        }
    }

    float aow[4];
#pragma unroll
    for (int ni = 0; ni < 4; ++ni) aow[ni] = ao[b * 512 + n0 + wn * 64 + ni * 16 + lr];
#pragma unroll
    for (int mi = 0; mi < 4; ++mi) {
#pragma unroll
        for (int r = 0; r < 4; ++r) {
            float p = 0.f;
#pragma unroll
            for (int ni = 0; ni < 4; ++ni) p += fast_tanh(acc[mi][ni][r]) * aow[ni];
            p += __shfl_xor(p, 1, 16);
            p += __shfl_xor(p, 2, 16);
            p += __shfl_xor(p, 4, 16);
            p += __shfl_xor(p, 8, 16);
            if (lr == 0)
                atomicAdd(&logit[(size_t)m0 + wm * 64 + mi * 16 + lq * 4 + r], p);
        }
    }
}

// Fallback gen (paired with k_copyseq when no ebf)
__global__ __launch_bounds__(256) void k_gen(const unsigned short* aob, const float* W_gen,
                                             float* out, float* rowsum) {
    __shared__ __align__(16) unsigned char smem[32768];
    f32x4 acc[4];
    const int d = blockIdx.x;
    const int l = (d & 7) * 391 + (d >> 3);
    const int m0 = (l & 3) * 64;
    const int n0 = (l >> 2) * 64;
    gemm_main<true>(aob, 512, W_gen, 512, 8, 0, V_ - 1, m0, n0, smem, acc);
    const int tid = threadIdx.x, w = tid >> 6, lane = tid & 63, lq = lane >> 4, lr = lane & 15;
    float rp[4] = {0.f, 0.f, 0.f, 0.f};
#pragma unroll
    for (int ns = 0; ns < 4; ++ns) {
        const int n = n0 + ns * 16 + lr;
        if (n < V_) {
#pragma unroll
            for (int r = 0; r < 4; ++r) {
                const float v = __expf(acc[ns][r]);
                out[(size_t)(m0 + w * 16 + lq * 4 + r) * VX_ + n] = v;
                rp[r] += v;
            }
        }
    }
#pragma unroll
    for (int r = 0; r < 4; ++r) {
        rp[r] += __shfl_xor(rp[r], 1, 16);
        rp[r] += __shfl_xor(rp[r], 2, 16);
        rp[r] += __shfl_xor(rp[r], 4, 16);
        rp[r] += __shfl_xor(rp[r], 8, 16);
    }
    if (lr == 0) {
#pragma unroll
        for (int r = 0; r < 4; ++r) atomicAdd(&rowsum[m0 + w * 16 + lq * 4 + r], rp[r]);
    }
}

__global__ __launch_bounds__(256) void k_scatter(const float* logit, const int* stok,
                                                 const void* maskp, const int* flagp,
                                                 float* out, float* rowsum) {
    const int idx = blockIdx.x * 256 + threadIdx.x;
    const int b = idx >> 9;
    const int flag = *flagp;
    float v = 0.f;
    if (!get_mask(maskp, flag, idx)) {
        v = __expf(logit[idx]);
        atomicAdd(&out[(size_t)b * VX_ + stok[idx]], v);
    }
    float s = v;
#pragma unroll
    for (int o = 1; o < 64; o <<= 1) s += __shfl_xor(s, o, 64);
    if ((threadIdx.x & 63) == 0) atomicAdd(&rowsum[b], s);
}

// float4 log pass: VX_ = 50100 = 4*12525; each row 16B-aligned (200400 % 16 == 0)
__global__ __launch_bounds__(256) void k_final(float* out, const float* rowsum) {
    const int b = blockIdx.y;
    const float ls = __logf(rowsum[b]);
    const int p = blockIdx.x * 256 + threadIdx.x;
    if (p < 12525) {
        float4* o4 = (float4*)(out + (size_t)b * VX_) + p;
        float4 v = *o4;
        v.x = __logf(v.x) - ls;
        v.y = __logf(v.y) - ls;
        v.z = __logf(v.z) - ls;
        v.w = __logf(v.w) - ls;
        *o4 = v;
    }
}

// ---- host ------------------------------------------------------------------

extern "C" void kernel_launch(void* const* d_in, const int* in_sizes, int n_in, void* d_out,
                              int out_size, void* d_ws, size_t ws_size, hipStream_t stream) {
    const float* embedding = (const float*)d_in[0];
    const float* W_ih = (const float*)d_in[1];
    const float* W_hh = (const float*)d_in[2];
    const float* b_ih = (const float*)d_in[3];
    const float* b_hh = (const float*)d_in[4];
    const float* W_attn = (const float*)d_in[5];
    const float* W_out = (const float*)d_in[6];
    const float* b_out = (const float*)d_in[7];
    const float* W_copy = (const float*)d_in[8];
    // d_in[9] = W_incopy: provably dead in the reference (tanh(0)=0 on unmatched,
    // matched positions masked to -inf => softmax is uniform over unmatched).
    const float* W_gen = (const float*)d_in[10];
    const float* enc = (const float*)d_in[11];
    const float* pcs = (const float*)d_in[12];
    const float* h0 = (const float*)d_in[13];
    const float* c0 = (const float*)d_in[14];
    const int* ptok = (const int*)d_in[15];
    const int* stok = (const int*)d_in[16];
    const void* maskp = d_in[17];
    float* out = (float*)d_out;

    char* ws = (char*)d_ws;
    size_t off = 0;
    auto alloc = [&](size_t bytes) {
        size_t o = off;
        off += (bytes + 255) & ~(size_t)255;
        return o;
    };
    int* flag = (int*)(ws + alloc(4));
    float* rowsum = (float*)(ws + alloc(B_ * 4));
    float* cs_sum = (float*)(ws + alloc((size_t)1024 * SRC_ * 4));
    int* cs_cnt = (int*)(ws + alloc(1024 * 4));
    unsigned short* xh = (unsigned short*)(ws + alloc((size_t)B_ * KXH * 2));
    unsigned short* Wg = (unsigned short*)(ws + alloc((size_t)2048 * KXH * 2));
    unsigned short* Wcb = (unsigned short*)(ws + alloc((size_t)512 * 512 * 2));
    float* gates = (float*)(ws + alloc((size_t)B_ * 2048 * 4));
    unsigned short* h1b = (unsigned short*)(ws + alloc((size_t)B_ * 512 * 2));
    float* qbuf = (float*)(ws + alloc((size_t)B_ * 512 * 4));
    unsigned short* ch = (unsigned short*)(ws + alloc((size_t)B_ * 1024 * 2));
    unsigned short* aob = (unsigned short*)(ws + alloc((size_t)B_ * 512 * 2));
    float* logit = (float*)(ws + alloc((size_t)B_ * S_ * 4));
    const size_t ebf_bytes = (size_t)B_ * S_ * SRC_ * 2;  // 134 MB
    const int use_ebf = (off + ebf_bytes <= ws_size) ? 1 : 0;
    unsigned short* ebf = (unsigned short*)(ws + off);
    (void)n_in; (void)in_sizes; (void)out_size;

    hipLaunchKernelGGL(k_pre, dim3(2662), dim3(256), 0, stream, enc, stok, ptok, cs_sum, cs_cnt,
                       ebf, use_ebf, logit, rowsum, maskp, flag, out, W_ih, W_hh, W_copy, Wg,
                       Wcb, gates);
    hipLaunchKernelGGL(k_cs_final, dim3(256), dim3(256), 0, stream, cs_sum, cs_cnt, embedding,
                       ptok, pcs, h0, xh);
    hipLaunchKernelGGL(k_gates, dim3(4, 32, 2), dim3(256), 0, stream, xh, Wg, gates);
    hipLaunchKernelGGL(k_lstm, dim3(512), dim3(256), 0, stream, gates, b_ih, b_hh, c0, out, h1b);
    hipLaunchKernelGGL(k_q, dim3(4, 8), dim3(256), 0, stream, h1b, W_attn, qbuf);
    hipLaunchKernelGGL(k_attn3, dim3(256), dim3(1024), 0, stream, enc, ebf, use_ebf, qbuf,
                       maskp, flag, h1b, ch);
    hipLaunchKernelGGL(k_attnout, dim3(4, 8), dim3(256), 0, stream, ch, W_out, b_out, out, aob);
    if (use_ebf) {
        hipLaunchKernelGGL(k_tail, dim3(7224), dim3(256), 0, stream, ebf, Wcb, out + ATT_OFF,
                           aob, W_gen, maskp, flag, out, logit, rowsum);
    } else {
        hipLaunchKernelGGL(k_gen, dim3(3128), dim3(256), 0, stream, aob, W_gen, out, rowsum);
        hipLaunchKernelGGL(k_copyseq, dim3(1024, 4), dim3(256), 0, stream, enc, Wcb,
                           out + ATT_OFF, maskp, flag, logit);
    }
    hipLaunchKernelGGL(k_scatter, dim3(512), dim3(256), 0, stream, logit, stok, maskp, flag,
                       out, rowsum);
    hipLaunchKernelGGL(k_final, dim3(49, 256), dim3(256), 0, stream, out, rowsum);
}

// Round 15
// 393.239 us; speedup vs baseline: 1.0261x; 1.0015x over previous
//
#include <hip/hip_runtime.h>
#include <hip/hip_bf16.h>
#include <math.h>

#define V_ 50000
#define OOV_ 100
#define VX_ 50100
#define B_ 256
#define S_ 512
#define TH_ 512
#define SRC_ 512
#define KXH 1664

#define ATT_OFF ((size_t)B_ * VX_)
#define H1_OFF (ATT_OFF + (size_t)B_ * TH_)
#define C1_OFF (H1_OFF + (size_t)B_ * TH_)

typedef float f32x4 __attribute__((ext_vector_type(4)));
typedef short s16x8 __attribute__((ext_vector_type(8)));

__device__ __forceinline__ unsigned short f2bf(float f) {
    unsigned int u = __float_as_uint(f);
    u += 0x7FFFu + ((u >> 16) & 1u);
    return (unsigned short)(u >> 16);
}
// packed f32x2 -> bf16x2 (RNE, same rounding as f2bf); compiler emits cvt_pk
__device__ __forceinline__ unsigned int pk2bf(float x, float y) {
    __hip_bfloat162 h = __float22bfloat162_rn(make_float2(x, y));
    return *reinterpret_cast<unsigned int*>(&h);
}
__device__ __forceinline__ float fast_tanh(float x) {
    return 1.0f - 2.0f / (__expf(2.0f * x) + 1.0f);
}
__device__ __forceinline__ float sigm(float x) { return 1.0f / (1.0f + __expf(-x)); }

__device__ __forceinline__ bool get_mask(const void* m, int flag, size_t idx) {
    return flag ? (((const unsigned char*)m)[idx] != 0)
                : (((const int*)m)[idx] != 0);
}

// Builtin MFMA: compiler models MFMA->VALU hazards (inline-asm version corrupted
// accumulators -- round 1->2 lesson).
__device__ __forceinline__ void mfma_acc(f32x4& c, s16x8 a, s16x8 b) {
    c = __builtin_amdgcn_mfma_f32_16x16x32_bf16(a, b, c, 0, 0, 0);
}

// ---- staging helpers -------------------------------------------------------
// LDS tile layout: [rows][128 bytes], swizzle: byte ^= ((row&7)<<4)

__device__ __forceinline__ void stage_bf16(const unsigned short* src, int ld,
                                           int row0, int k0, unsigned char* ldsbase) {
    const int tid = threadIdx.x;
    const int w = tid >> 6, lane = tid & 63;
#pragma unroll
    for (int jj = 0; jj < 2; ++jj) {
        const int qq = w * 2 + jj;               // 0..7, wave-uniform
        const int rowl = qq * 8 + (lane >> 3);
        const int su = (lane & 7) ^ (rowl & 7);  // pre-swizzled global source
        const unsigned short* g = src + (size_t)(row0 + rowl) * ld + k0 + su * 8;
        __builtin_amdgcn_global_load_lds(
            (const __attribute__((address_space(1))) void*)g,
            (__attribute__((address_space(3))) void*)(ldsbase + qq * 1024), 16, 0, 0);
    }
}

// 128-row variant (16 KB tile), same layout/swizzle
__device__ __forceinline__ void stage_bf16_128(const unsigned short* src, int ld,
                                               int k0, unsigned char* ldsbase) {
    const int tid = threadIdx.x;
    const int w = tid >> 6, lane = tid & 63;
#pragma unroll
    for (int jj = 0; jj < 4; ++jj) {
        const int qq = w * 4 + jj;               // 0..15, wave-uniform
        const int rowl = qq * 8 + (lane >> 3);   // 0..127
        const int su = (lane & 7) ^ (rowl & 7);
        const unsigned short* g = src + (size_t)rowl * ld + k0 + su * 8;
        __builtin_amdgcn_global_load_lds(
            (const __attribute__((address_space(1))) void*)g,
            (__attribute__((address_space(3))) void*)(ldsbase + qq * 1024), 16, 0, 0);
    }
}

__device__ __forceinline__ void stage_f32(const float* src, int ld, int row0, int k0,
                                          int rowmax, unsigned char* ldsbase) {
    const int tid = threadIdx.x;
#pragma unroll
    for (int it = 0; it < 4; ++it) {
        const int p = it * 256 + tid;
        const int row = p >> 4;
        const int u4 = p & 15;
        int gr = row0 + row;
        gr = gr > rowmax ? rowmax : gr;
        const float4 v = *(const float4*)(src + (size_t)gr * ld + k0 + u4 * 4);
        *(uint2*)(ldsbase + row * 128 + ((u4 * 8) ^ ((row & 7) << 4))) =
            make_uint2(pk2bf(v.x, v.y), pk2bf(v.z, v.w));
    }
}

__device__ __forceinline__ void compute64(const unsigned char* Ab, const unsigned char* Bb,
                                          f32x4 acc[4]) {
    const int tid = threadIdx.x;
    const int w = tid >> 6, lane = tid & 63, lq = lane >> 4, lr = lane & 15;
#pragma unroll
    for (int ks = 0; ks < 2; ++ks) {
        const int kb = ks * 64 + lq * 16;
        const int ar = w * 16 + lr;
        s16x8 a = *(const s16x8*)(Ab + ar * 128 + (kb ^ ((ar & 7) << 4)));
#pragma unroll
        for (int ns = 0; ns < 4; ++ns) {
            const int br = ns * 16 + lr;
            s16x8 b = *(const s16x8*)(Bb + br * 128 + (kb ^ ((br & 7) << 4)));
            mfma_acc(acc[ns], a, b);
        }
    }
}

// Generic 64x64-tile GEMM core with 1-deep prefetch double-buffer (32 KB LDS).
// One barrier per K-step: barrier drains prev-iter loads into the buffer about
// to be computed; next-iter loads are issued into the other buffer and stay in
// flight across the compute (r5/r8-proven pattern; removing it cost ~10-15 us).
template <bool BF32>
__device__ __forceinline__ void gemm_main(const unsigned short* A, int lda, const void* Bp,
                                          int ldb, int nkc, int kbase, int rowmaxB, int m0,
                                          int n0, unsigned char* smem, f32x4 acc[4]) {
#pragma unroll
    for (int i = 0; i < 4; ++i) acc[i] = f32x4{0.f, 0.f, 0.f, 0.f};
    unsigned char* const A0 = smem;
    unsigned char* const A1 = smem + 8192;
    unsigned char* const B0 = smem + 16384;
    unsigned char* const B1 = smem + 24576;
    stage_bf16(A, lda, m0, kbase, A0);
    if (BF32) stage_f32((const float*)Bp, ldb, n0, kbase, rowmaxB, B0);
    else      stage_bf16((const unsigned short*)Bp, ldb, n0, kbase, B0);
    for (int kc = 0; kc < nkc; ++kc) {
        __syncthreads();   // drains loads for this kc's buffers
        const unsigned char* Ac = (kc & 1) ? A1 : A0;
        const unsigned char* Bc = (kc & 1) ? B1 : B0;
        if (kc + 1 < nkc) {
            const int k0 = kbase + (kc + 1) * 64;
            stage_bf16(A, lda, m0, k0, (kc & 1) ? A0 : A1);
            if (BF32) stage_f32((const float*)Bp, ldb, n0, k0, rowmaxB, (kc & 1) ? B0 : B1);
            else      stage_bf16((const unsigned short*)Bp, ldb, n0, k0, (kc & 1) ? B0 : B1);
        }
        compute64(Ac, Bc, acc);
    }
}

// ---- kernels ---------------------------------------------------------------

// Fused prelude: all mutually-independent setup work in ONE launch.
__global__ __launch_bounds__(256) void k_pre(const float* enc, const int* stok, const int* ptok,
                                             float* cs_sum, int* cs_cnt, unsigned short* ebf,
                                             int do_cvt, float* logit, float* rowsum,
                                             const void* maskp, int* flag, float* out,
                                             const float* W_ih, const float* W_hh,
                                             const float* W_copy, unsigned short* Wg,
                                             unsigned short* Wcb, float* gates) {
    const int bid = blockIdx.x, tid = threadIdx.x;
    if (bid < 1024) {
        __shared__ float comb[512];
        __shared__ int cc[2];
        const int b = bid >> 2, chunk = bid & 3;
        const int h = tid >> 7, d0 = (tid & 127) * 4;
        const int prev = ptok[b];
        const float* base = enc + ((size_t)b * S_ + chunk * 128) * SRC_;
        const int* st = stok + b * S_ + chunk * 128;
        unsigned short* eb = ebf + ((size_t)b * S_ + chunk * 128) * SRC_;
        float a0 = 0.f, a1 = 0.f, a2 = 0.f, a3 = 0.f;
        int cnt = 0;
        for (int s2 = 0; s2 < 64; ++s2) {
            const int s = s2 * 2 + h;
            const float4 v = *(const float4*)(base + (size_t)s * SRC_ + d0);
            if (st[s] != prev) { a0 += v.x; a1 += v.y; a2 += v.z; a3 += v.w; ++cnt; }
            if (do_cvt) {
                *(uint2*)(eb + (size_t)s * SRC_ + d0) =
                    make_uint2(pk2bf(v.x, v.y), pk2bf(v.z, v.w));
            }
        }
        if (h == 0) {
            comb[d0] = a0; comb[d0 + 1] = a1; comb[d0 + 2] = a2; comb[d0 + 3] = a3;
            if (tid == 0) cc[0] = cnt;
        }
        __syncthreads();
        if (h == 1) {
            comb[d0] += a0; comb[d0 + 1] += a1; comb[d0 + 2] += a2; comb[d0 + 3] += a3;
            if (tid == 128) cc[1] = cnt;
        }
        __syncthreads();
        cs_sum[(size_t)bid * SRC_ + tid] = comb[tid];
        cs_sum[(size_t)bid * SRC_ + 256 + tid] = comb[256 + tid];
        if (tid == 0) cs_cnt[bid] = cc[0] + cc[1];
    } else if (bid < 1536) {
        logit[(bid - 1024) * 256 + tid] = 0.f;
    } else if (bid == 1536) {
        rowsum[tid] = (float)OOV_;
    } else if (bid == 1537) {
        __shared__ int sfl;
        if (tid == 0) sfl = 0;
        __syncthreads();
        const uint4* m4 = (const uint4*)maskp;
        unsigned int ev = 0;
        for (int i = tid; i < (B_ * S_) / 16; i += 256) {
            const uint4 u = m4[i];
            ev |= (u.x | u.y | u.z | u.w) & 0xFFFFFF00u;
        }
        if (ev) atomicOr(&sfl, 1);
        __syncthreads();
        if (tid == 0) *flag = sfl;   // 1 => bool(1B) layout, 0 => int32 layout
    } else if (bid < 1638) {
        const int p = (bid - 1538) * 256 + tid;
        if (p < B_ * OOV_) {
            const int b = p / OOV_, j = p - b * OOV_;
            out[(size_t)b * VX_ + V_ + j] = 1.0f;   // exp(0) base for OOV columns
        }
    } else if (bid < 2150) {
        const int NWG = 2048 * KXH;
        const int NTOT4 = (NWG + 512 * 512) / 4;
        for (int i4 = (bid - 1638) * 256 + tid; i4 < NTOT4; i4 += 512 * 256) {
            const int e = i4 * 4;
            float4 v;
            unsigned short* dst;
            if (e < NWG) {
                const int r = e / KXH, c = e - r * KXH;
                v = (c < 1152) ? *(const float4*)(W_ih + (size_t)r * 1152 + c)
                               : *(const float4*)(W_hh + (size_t)r * 512 + (c - 1152));
                dst = Wg + e;
            } else {
                v = *(const float4*)(W_copy + (e - NWG));
                dst = Wcb + (e - NWG);
            }
            *(uint2*)dst = make_uint2(pk2bf(v.x, v.y), pk2bf(v.z, v.w));
        }
    } else {
        ((float4*)gates)[(bid - 2150) * 256 + tid] = make_float4(0.f, 0.f, 0.f, 0.f);
    }
}

__global__ __launch_bounds__(256) void k_cs_final(const float* cs_sum, const int* cs_cnt,
                                                  const float* embedding, const int* ptok,
                                                  const float* pcs, const float* h0,
                                                  unsigned short* xh) {
    const int b = blockIdx.x, tid = threadIdx.x;
    const int cnt = cs_cnt[b * 4] + cs_cnt[b * 4 + 1] + cs_cnt[b * 4 + 2] + cs_cnt[b * 4 + 3];
    const float inv = 1.f / (float)cnt;
    unsigned short* row = xh + (size_t)b * KXH;
    for (int d = tid; d < 512; d += 256) {
        float s = cs_sum[(size_t)(b * 4 + 0) * SRC_ + d] + cs_sum[(size_t)(b * 4 + 1) * SRC_ + d] +
                  cs_sum[(size_t)(b * 4 + 2) * SRC_ + d] + cs_sum[(size_t)(b * 4 + 3) * SRC_ + d];
        row[640 + d] = f2bf(s * inv);              // copy_state
        row[128 + d] = f2bf(pcs[b * 512 + d]);     // prev_context_state
        row[1152 + d] = f2bf(h0[b * 512 + d]);     // h0 (for W_hh part)
    }
    if (tid < 128) {
        int tk = ptok[b];
        if (tk >= V_) tk = 1;  // UNK
        row[tid] = f2bf(embedding[(size_t)tk * 128 + tid]);
    }
}

// split-K=2: each half atomicAdds into zero-initialized gates. Exactly 2
// commutative float adds per element onto exact 0 -> deterministic.
__global__ __launch_bounds__(256) void k_gates(const unsigned short* xh, const unsigned short* Wg,
                                               float* gates) {
    __shared__ __align__(16) unsigned char smem[32768];
    f32x4 acc[4];
    const int m0 = blockIdx.x * 64, n0 = blockIdx.y * 64;
    const int kb = blockIdx.z ? 832 : 0;
    gemm_main<false>(xh, KXH, Wg, KXH, 13, kb, 2047, m0, n0, smem, acc);
    const int tid = threadIdx.x, w = tid >> 6, lane = tid & 63, lq = lane >> 4, lr = lane & 15;
#pragma unroll
    for (int ns = 0; ns < 4; ++ns) {
        const int n = n0 + ns * 16 + lr;
#pragma unroll
        for (int r = 0; r < 4; ++r) {
            const int m = m0 + w * 16 + lq * 4 + r;
            atomicAdd(&gates[(size_t)m * 2048 + n], acc[ns][r]);
        }
    }
}

__global__ __launch_bounds__(256) void k_lstm(const float* gates, const float* b_ih,
                                              const float* b_hh, const float* c0, float* out,
                                              unsigned short* h1b) {
    const int idx = blockIdx.x * 256 + threadIdx.x;  // 0..131071
    const int b = idx >> 9, h = idx & 511;
    const float gi = gates[(size_t)b * 2048 + h] + b_ih[h] + b_hh[h];
    const float gf = gates[(size_t)b * 2048 + 512 + h] + b_ih[512 + h] + b_hh[512 + h];
    const float gg = gates[(size_t)b * 2048 + 1024 + h] + b_ih[1024 + h] + b_hh[1024 + h];
    const float go = gates[(size_t)b * 2048 + 1536 + h] + b_ih[1536 + h] + b_hh[1536 + h];
    const float c1 = sigm(gf) * c0[idx] + sigm(gi) * fast_tanh(gg);
    const float h1 = sigm(go) * fast_tanh(c1);
    out[H1_OFF + idx] = h1;
    out[C1_OFF + idx] = c1;
    h1b[idx] = f2bf(h1);
}

__global__ __launch_bounds__(256) void k_q(const unsigned short* h1b, const float* W_attn,
                                           float* qbuf) {
    __shared__ __align__(16) unsigned char smem[32768];
    f32x4 acc[4];
    const int m0 = blockIdx.x * 64, n0 = blockIdx.y * 64;
    gemm_main<true>(h1b, 512, W_attn, 512, 8, 0, 511, m0, n0, smem, acc);
    const int tid = threadIdx.x, w = tid >> 6, lane = tid & 63, lq = lane >> 4, lr = lane & 15;
#pragma unroll
    for (int ns = 0; ns < 4; ++ns) {
        const int n = n0 + ns * 16 + lr;
#pragma unroll
        for (int r = 0; r < 4; ++r)
            qbuf[(size_t)(m0 + w * 16 + lq * 4 + r) * 512 + n] = acc[ns][r];
    }
}

// Fused attention: 16 waves/block, wave w owns s-rows [w*32, w*32+32) with
// register-resident online softmax; single LDS merge replaces the parts/md
// global round-trip and the separate merge kernel.
__global__ __launch_bounds__(1024) void k_attn3(const float* enc, const unsigned short* ebf,
                                                const int use_ebf, const float* qv,
                                                const void* maskp, const int* flagp,
                                                const unsigned short* h1b, unsigned short* ch) {
    __shared__ float plds[16][512];
    __shared__ float mdl[16][2];
    const int b = blockIdx.x;
    const int tid = threadIdx.x, w = tid >> 6, lane = tid & 63;
    const int flag = *flagp;
    float q0[8];
    {
        const float4 t0 = *(const float4*)(qv + b * 512 + lane * 8);
        const float4 t1 = *(const float4*)(qv + b * 512 + lane * 8 + 4);
        q0[0] = t0.x; q0[1] = t0.y; q0[2] = t0.z; q0[3] = t0.w;
        q0[4] = t1.x; q0[5] = t1.y; q0[6] = t1.z; q0[7] = t1.w;
    }
    float M = -INFINITY, den = 0.f;
    float cv[8] = {0.f, 0.f, 0.f, 0.f, 0.f, 0.f, 0.f, 0.f};
    const int s0 = w * 32;
    for (int i = 0; i < 32; ++i) {
        const int s = s0 + i;
        if (get_mask(maskp, flag, (size_t)b * S_ + s)) continue;  // wave-uniform
        float v[8];
        if (use_ebf) {
            const uint4 u = *(const uint4*)(ebf + ((size_t)b * S_ + s) * 512 + lane * 8);
            v[0] = __uint_as_float(u.x << 16);
            v[1] = __uint_as_float(u.x & 0xffff0000u);
            v[2] = __uint_as_float(u.y << 16);
            v[3] = __uint_as_float(u.y & 0xffff0000u);
            v[4] = __uint_as_float(u.z << 16);
            v[5] = __uint_as_float(u.z & 0xffff0000u);
            v[6] = __uint_as_float(u.w << 16);
            v[7] = __uint_as_float(u.w & 0xffff0000u);
        } else {
            const float4 t0 = *(const float4*)(enc + ((size_t)b * S_ + s) * 512 + lane * 8);
            const float4 t1 = *(const float4*)(enc + ((size_t)b * S_ + s) * 512 + lane * 8 + 4);
            v[0] = t0.x; v[1] = t0.y; v[2] = t0.z; v[3] = t0.w;
            v[4] = t1.x; v[5] = t1.y; v[6] = t1.z; v[7] = t1.w;
        }
        float a = 0.f;
#pragma unroll
        for (int j = 0; j < 8; ++j) a += q0[j] * v[j];
        a += __shfl_xor(a, 1);
        a += __shfl_xor(a, 2);
        a += __shfl_xor(a, 4);
        a += __shfl_xor(a, 8);
        a += __shfl_xor(a, 16);
        a += __shfl_xor(a, 32);
        const float nM = fmaxf(M, a);
        const float sc = __expf(M - nM);   // M=-inf -> 0
        const float p = __expf(a - nM);
        den = den * sc + p;
#pragma unroll
        for (int j = 0; j < 8; ++j) cv[j] = cv[j] * sc + p * v[j];
        M = nM;
    }
    if (lane == 0) { mdl[w][0] = M; mdl[w][1] = den; }
    *(float4*)&plds[w][lane * 8] = make_float4(cv[0], cv[1], cv[2], cv[3]);
    *(float4*)&plds[w][lane * 8 + 4] = make_float4(cv[4], cv[5], cv[6], cv[7]);
    __syncthreads();
    if (tid < 512) {
        float Mg = -INFINITY;
#pragma unroll
        for (int j = 0; j < 16; ++j) Mg = fmaxf(Mg, mdl[j][0]);
        float deng = 0.f, c = 0.f;
#pragma unroll
        for (int j = 0; j < 16; ++j) {
            const float sc = __expf(mdl[j][0] - Mg);  // -inf -> 0
            deng += mdl[j][1] * sc;
            c += plds[j][tid] * sc;
        }
        ch[(size_t)b * 1024 + tid] = f2bf(c / deng);
    } else {
        ch[(size_t)b * 1024 + tid] = h1b[b * 512 + (tid - 512)];
    }
}

__global__ __launch_bounds__(256) void k_attnout(const unsigned short* ch, const float* W_out,
                                                 const float* b_out, float* out,
                                                 unsigned short* aob) {
    __shared__ __align__(16) unsigned char smem[32768];
    f32x4 acc[4];
    const int m0 = blockIdx.x * 64, n0 = blockIdx.y * 64;
    gemm_main<true>(ch, 1024, W_out, 1024, 16, 0, 511, m0, n0, smem, acc);
    const int tid = threadIdx.x, w = tid >> 6, lane = tid & 63, lq = lane >> 4, lr = lane & 15;
#pragma unroll
    for (int ns = 0; ns < 4; ++ns) {
        const int n = n0 + ns * 16 + lr;
        const float bb = b_out[n];
#pragma unroll
        for (int r = 0; r < 4; ++r) {
            const int m = m0 + w * 16 + lq * 4 + r;
            const float t = fast_tanh(acc[ns][r] + bb);
            out[ATT_OFF + (size_t)m * 512 + n] = t;
            aob[(size_t)m * 512 + n] = f2bf(t);
        }
    }
}

// Fused tail (r8 structure): copyseq blocks [0,4096), XCD-swizzled, 1-deep
// global_load_lds double-buffer on BOTH operands (64 KB, 0 bank conflicts);
// gen blocks [4096,7224), XCD-swizzled, prefetched gemm_main.
__global__ __launch_bounds__(256) void k_tail(const unsigned short* ebf,
                                              const unsigned short* Wcb, const float* ao,
                                              const unsigned short* aob, const float* W_gen,
                                              const void* maskp, const int* flagp, float* out,
                                              float* logit, float* rowsum) {
    __shared__ __align__(16) unsigned char smem[65536];
    const int tid = threadIdx.x;
    const int w = tid >> 6, lane = tid & 63;
    const int lq = lane >> 4, lr = lane & 15;

    if (blockIdx.x < 4096) {
        // ---- copy_seq GEMM ----
        const int d = blockIdx.x;                  // 0..4095
        const int l = (d & 7) * 512 + (d >> 3);    // bijective (4096 = 8*512)
        const int n0 = (l & 3) * 128;
        const int mt = l >> 2;
        const int m0 = mt * 128;
        const int b = mt >> 2;
        if (get_mask(maskp, *flagp, (size_t)b * S_ + (m0 & 511))) return;  // tile masked
        unsigned char* const A0 = smem;
        unsigned char* const A1 = smem + 16384;
        unsigned char* const B0 = smem + 32768;
        unsigned char* const B1 = smem + 49152;
        const int wm = w >> 1, wn = w & 1;
        const unsigned short* Asrc = ebf + (size_t)m0 * 512;
        const unsigned short* Bsrc = Wcb + (size_t)n0 * 512;

        f32x4 acc[4][4];
#pragma unroll
        for (int mi = 0; mi < 4; ++mi)
#pragma unroll
            for (int ni = 0; ni < 4; ++ni) acc[mi][ni] = f32x4{0.f, 0.f, 0.f, 0.f};

        stage_bf16_128(Asrc, 512, 0, A0);
        stage_bf16_128(Bsrc, 512, 0, B0);

        for (int kc = 0; kc < 8; ++kc) {
            __syncthreads();   // drains loads issued for this kc (vmcnt0 at barrier)
            const unsigned char* Ac = (kc & 1) ? A1 : A0;
            const unsigned char* Bc = (kc & 1) ? B1 : B0;
            if (kc < 7) {      // issue next-kc loads; they drain at NEXT barrier
                stage_bf16_128(Asrc, 512, (kc + 1) * 64, (kc & 1) ? A0 : A1);
                stage_bf16_128(Bsrc, 512, (kc + 1) * 64, (kc & 1) ? B0 : B1);
            }
#pragma unroll
            for (int ks = 0; ks < 2; ++ks) {
                const int kb = ks * 64 + lq * 16;
                s16x8 afr[4], bfr[4];
#pragma unroll
                for (int mi = 0; mi < 4; ++mi) {
                    const int ar = wm * 64 + mi * 16 + lr;
                    afr[mi] = *(const s16x8*)(Ac + ar * 128 + (kb ^ ((ar & 7) << 4)));
                }
#pragma unroll
                for (int ni = 0; ni < 4; ++ni) {
                    const int br = wn * 64 + ni * 16 + lr;
                    bfr[ni] = *(const s16x8*)(Bc + br * 128 + (kb ^ ((br & 7) << 4)));
                }
#pragma unroll
                for (int mi = 0; mi < 4; ++mi)
#pragma unroll
                    for (int ni = 0; ni < 4; ++ni) mfma_acc(acc[mi][ni], afr[mi], bfr[ni]);
            }
        }

        // epilogue: logit[s] += sum over this wave's 64 n-cols of tanh(P)*ao
        float aow[4];
#pragma unroll
        for (int ni = 0; ni < 4; ++ni) aow[ni] = ao[b * 512 + n0 + wn * 64 + ni * 16 + lr];
#pragma unroll
        for (int mi = 0; mi < 4; ++mi) {
#pragma unroll
            for (int r = 0; r < 4; ++r) {
                float p = 0.f;
#pragma unroll
                for (int ni = 0; ni < 4; ++ni) p += fast_tanh(acc[mi][ni][r]) * aow[ni];
                p += __shfl_xor(p, 1, 16);
                p += __shfl_xor(p, 2, 16);
                p += __shfl_xor(p, 4, 16);
                p += __shfl_xor(p, 8, 16);
                if (lr == 0)
                    atomicAdd(&logit[(size_t)m0 + wm * 64 + mi * 16 + lq * 4 + r], p);
            }
        }
    } else {
        // ---- gen GEMM + exp + rowsum ----
        const int d = blockIdx.x - 4096;           // 0..3127
        const int l = (d & 7) * 391 + (d >> 3);    // bijective (3128 = 8*391)
        const int m0 = (l & 3) * 64;
        const int n0 = (l >> 2) * 64;
        f32x4 acc[4];
        gemm_main<true>(aob, 512, W_gen, 512, 8, 0, V_ - 1, m0, n0, smem, acc);
        float rp[4] = {0.f, 0.f, 0.f, 0.f};
#pragma unroll
        for (int ns = 0; ns < 4; ++ns) {
            const int n = n0 + ns * 16 + lr;
            if (n < V_) {
#pragma unroll
                for (int r = 0; r < 4; ++r) {
                    const float v = __expf(acc[ns][r]);
                    out[(size_t)(m0 + w * 16 + lq * 4 + r) * VX_ + n] = v;
                    rp[r] += v;
                }
            }
        }
#pragma unroll
        for (int r = 0; r < 4; ++r) {
            rp[r] += __shfl_xor(rp[r], 1, 16);
            rp[r] += __shfl_xor(rp[r], 2, 16);
            rp[r] += __shfl_xor(rp[r], 4, 16);
            rp[r] += __shfl_xor(rp[r], 8, 16);
        }
        if (lr == 0) {
#pragma unroll
            for (int r = 0; r < 4; ++r) atomicAdd(&rowsum[m0 + w * 16 + lq * 4 + r], rp[r]);
        }
    }
}

// Fallback (ws too small for ebf): f32 enc, single-buffer, reg-staged A convert.
__global__ __launch_bounds__(256) void k_copyseq(const float* enc, const unsigned short* Wcb,
                                                 const float* ao, const void* maskp,
                                                 const int* flagp, float* logit) {
    const int m0 = blockIdx.x * 128;
    const int n0 = blockIdx.y * 128;
    const int b = blockIdx.x >> 2;
    if (get_mask(maskp, *flagp, (size_t)b * S_ + (m0 & 511))) return;
    __shared__ __align__(16) unsigned char smem[32768];
    unsigned char* const A0 = smem;
    unsigned char* const B0 = smem + 16384;
    const int tid = threadIdx.x;
    const int w = tid >> 6, lane = tid & 63;
    const int wm = w >> 1, wn = w & 1, lq = lane >> 4, lr = lane & 15;
    const float* Asrc = enc + (size_t)m0 * 512;

    f32x4 acc[4][4];
#pragma unroll
    for (int mi = 0; mi < 4; ++mi)
#pragma unroll
        for (int ni = 0; ni < 4; ++ni) acc[mi][ni] = f32x4{0.f, 0.f, 0.f, 0.f};

    const int arow_t = tid >> 3, au_t = tid & 7;
    for (int kc = 0; kc < 8; ++kc) {
        __syncthreads();
        const int k0 = kc * 64;
#pragma unroll
        for (int it = 0; it < 4; ++it) {
            const int row = arow_t + it * 32;
            const float* g = Asrc + (size_t)row * 512 + k0 + au_t * 8;
            const float4 v0 = *(const float4*)g;
            const float4 v1 = *(const float4*)(g + 4);
            uint4 pk;
            pk.x = pk2bf(v0.x, v0.y);
            pk.y = pk2bf(v0.z, v0.w);
            pk.z = pk2bf(v1.x, v1.y);
            pk.w = pk2bf(v1.z, v1.w);
            *(uint4*)(A0 + row * 128 + ((au_t * 16) ^ ((row & 7) << 4))) = pk;
        }
        stage_bf16_128(Wcb + (size_t)n0 * 512, 512, k0, B0);
        __syncthreads();
#pragma unroll
        for (int ks = 0; ks < 2; ++ks) {
            const int kb = ks * 64 + lq * 16;
            s16x8 afr[4], bfr[4];
#pragma unroll
            for (int mi = 0; mi < 4; ++mi) {
                const int ar = wm * 64 + mi * 16 + lr;
                afr[mi] = *(const s16x8*)(A0 + ar * 128 + (kb ^ ((ar & 7) << 4)));
            }
#pragma unroll
            for (int ni = 0; ni < 4; ++ni) {
                const int br = wn * 64 + ni * 16 + lr;
                bfr[ni] = *(const s16x8*)(B0 + br * 128 + (kb ^ ((br & 7) << 4)));
            }
#pragma unroll
            for (int mi = 0; mi < 4; ++mi)
#pragma unroll
                for (int ni = 0; ni < 4; ++ni) mfma_acc(acc[mi][ni], afr[mi], bfr[ni]);
        }
    }

    float aow[4];
#pragma unroll
    for (int ni = 0; ni < 4; ++ni) aow[ni] = ao[b * 512 + n0 + wn * 64 + ni * 16 + lr];
#pragma unroll
    for (int mi = 0; mi < 4; ++mi) {
#pragma unroll
        for (int r = 0; r < 4; ++r) {
            float p = 0.f;
#pragma unroll
            for (int ni = 0; ni < 4; ++ni) p += fast_tanh(acc[mi][ni][r]) * aow[ni];
            p += __shfl_xor(p, 1, 16);
            p += __shfl_xor(p, 2, 16);
            p += __shfl_xor(p, 4, 16);
            p += __shfl_xor(p, 8, 16);
            if (lr == 0)
                atomicAdd(&logit[(size_t)m0 + wm * 64 + mi * 16 + lq * 4 + r], p);
        }
    }
}

// Fallback gen (paired with k_copyseq when no ebf)
__global__ __launch_bounds__(256) void k_gen(const unsigned short* aob, const float* W_gen,
                                             float* out, float* rowsum) {
    __shared__ __align__(16) unsigned char smem[32768];
    f32x4 acc[4];
    const int d = blockIdx.x;
    const int l = (d & 7) * 391 + (d >> 3);
    const int m0 = (l & 3) * 64;
    const int n0 = (l >> 2) * 64;
    gemm_main<true>(aob, 512, W_gen, 512, 8, 0, V_ - 1, m0, n0, smem, acc);
    const int tid = threadIdx.x, w = tid >> 6, lane = tid & 63, lq = lane >> 4, lr = lane & 15;
    float rp[4] = {0.f, 0.f, 0.f, 0.f};
#pragma unroll
    for (int ns = 0; ns < 4; ++ns) {
        const int n = n0 + ns * 16 + lr;
        if (n < V_) {
#pragma unroll
            for (int r = 0; r < 4; ++r) {
                const float v = __expf(acc[ns][r]);
                out[(size_t)(m0 + w * 16 + lq * 4 + r) * VX_ + n] = v;
                rp[r] += v;
            }
        }
    }
#pragma unroll
    for (int r = 0; r < 4; ++r) {
        rp[r] += __shfl_xor(rp[r], 1, 16);
        rp[r] += __shfl_xor(rp[r], 2, 16);
        rp[r] += __shfl_xor(rp[r], 4, 16);
        rp[r] += __shfl_xor(rp[r], 8, 16);
    }
    if (lr == 0) {
#pragma unroll
        for (int r = 0; r < 4; ++r) atomicAdd(&rowsum[m0 + w * 16 + lq * 4 + r], rp[r]);
    }
}

__global__ __launch_bounds__(256) void k_scatter(const float* logit, const int* stok,
                                                 const void* maskp, const int* flagp,
                                                 float* out, float* rowsum) {
    const int idx = blockIdx.x * 256 + threadIdx.x;
    const int b = idx >> 9;
    const int flag = *flagp;
    float v = 0.f;
    if (!get_mask(maskp, flag, idx)) {
        v = __expf(logit[idx]);
        atomicAdd(&out[(size_t)b * VX_ + stok[idx]], v);
    }
    float s = v;
#pragma unroll
    for (int o = 1; o < 64; o <<= 1) s += __shfl_xor(s, o, 64);
    if ((threadIdx.x & 63) == 0) atomicAdd(&rowsum[b], s);
}

// float4 log pass: VX_ = 50100 = 4*12525; each row 16B-aligned (200400 % 16 == 0)
__global__ __launch_bounds__(256) void k_final(float* out, const float* rowsum) {
    const int b = blockIdx.y;
    const float ls = __logf(rowsum[b]);
    const int p = blockIdx.x * 256 + threadIdx.x;
    if (p < 12525) {
        float4* o4 = (float4*)(out + (size_t)b * VX_) + p;
        float4 v = *o4;
        v.x = __logf(v.x) - ls;
        v.y = __logf(v.y) - ls;
        v.z = __logf(v.z) - ls;
        v.w = __logf(v.w) - ls;
        *o4 = v;
    }
}

// ---- host ------------------------------------------------------------------

extern "C" void kernel_launch(void* const* d_in, const int* in_sizes, int n_in, void* d_out,
                              int out_size, void* d_ws, size_t ws_size, hipStream_t stream) {
    const float* embedding = (const float*)d_in[0];
    const float* W_ih = (const float*)d_in[1];
    const float* W_hh = (const float*)d_in[2];
    const float* b_ih = (const float*)d_in[3];
    const float* b_hh = (const float*)d_in[4];
    const float* W_attn = (const float*)d_in[5];
    const float* W_out = (const float*)d_in[6];
    const float* b_out = (const float*)d_in[7];
    const float* W_copy = (const float*)d_in[8];
    // d_in[9] = W_incopy: provably dead in the reference (tanh(0)=0 on unmatched,
    // matched positions masked to -inf => softmax is uniform over unmatched).
    const float* W_gen = (const float*)d_in[10];
    const float* enc = (const float*)d_in[11];
    const float* pcs = (const float*)d_in[12];
    const float* h0 = (const float*)d_in[13];
    const float* c0 = (const float*)d_in[14];
    const int* ptok = (const int*)d_in[15];
    const int* stok = (const int*)d_in[16];
    const void* maskp = d_in[17];
    float* out = (float*)d_out;

    char* ws = (char*)d_ws;
    size_t off = 0;
    auto alloc = [&](size_t bytes) {
        size_t o = off;
        off += (bytes + 255) & ~(size_t)255;
        return o;
    };
    int* flag = (int*)(ws + alloc(4));
    float* rowsum = (float*)(ws + alloc(B_ * 4));
    float* cs_sum = (float*)(ws + alloc((size_t)1024 * SRC_ * 4));
    int* cs_cnt = (int*)(ws + alloc(1024 * 4));
    unsigned short* xh = (unsigned short*)(ws + alloc((size_t)B_ * KXH * 2));
    unsigned short* Wg = (unsigned short*)(ws + alloc((size_t)2048 * KXH * 2));
    unsigned short* Wcb = (unsigned short*)(ws + alloc((size_t)512 * 512 * 2));
    float* gates = (float*)(ws + alloc((size_t)B_ * 2048 * 4));
    unsigned short* h1b = (unsigned short*)(ws + alloc((size_t)B_ * 512 * 2));
    float* qbuf = (float*)(ws + alloc((size_t)B_ * 512 * 4));
    unsigned short* ch = (unsigned short*)(ws + alloc((size_t)B_ * 1024 * 2));
    unsigned short* aob = (unsigned short*)(ws + alloc((size_t)B_ * 512 * 2));
    float* logit = (float*)(ws + alloc((size_t)B_ * S_ * 4));
    const size_t ebf_bytes = (size_t)B_ * S_ * SRC_ * 2;  // 134 MB
    const int use_ebf = (off + ebf_bytes <= ws_size) ? 1 : 0;
    unsigned short* ebf = (unsigned short*)(ws + off);
    (void)n_in; (void)in_sizes; (void)out_size;

    hipLaunchKernelGGL(k_pre, dim3(2662), dim3(256), 0, stream, enc, stok, ptok, cs_sum, cs_cnt,
                       ebf, use_ebf, logit, rowsum, maskp, flag, out, W_ih, W_hh, W_copy, Wg,
                       Wcb, gates);
    hipLaunchKernelGGL(k_cs_final, dim3(256), dim3(256), 0, stream, cs_sum, cs_cnt, embedding,
                       ptok, pcs, h0, xh);
    hipLaunchKernelGGL(k_gates, dim3(4, 32, 2), dim3(256), 0, stream, xh, Wg, gates);
    hipLaunchKernelGGL(k_lstm, dim3(512), dim3(256), 0, stream, gates, b_ih, b_hh, c0, out, h1b);
    hipLaunchKernelGGL(k_q, dim3(4, 8), dim3(256), 0, stream, h1b, W_attn, qbuf);
    hipLaunchKernelGGL(k_attn3, dim3(256), dim3(1024), 0, stream, enc, ebf, use_ebf, qbuf,
                       maskp, flag, h1b, ch);
    hipLaunchKernelGGL(k_attnout, dim3(4, 8), dim3(256), 0, stream, ch, W_out, b_out, out, aob);
    if (use_ebf) {
        hipLaunchKernelGGL(k_tail, dim3(7224), dim3(256), 0, stream, ebf, Wcb, out + ATT_OFF,
                           aob, W_gen, maskp, flag, out, logit, rowsum);
    } else {
        hipLaunchKernelGGL(k_gen, dim3(3128), dim3(256), 0, stream, aob, W_gen, out, rowsum);
        hipLaunchKernelGGL(k_copyseq, dim3(1024, 4), dim3(256), 0, stream, enc, Wcb,
                           out + ATT_OFF, maskp, flag, logit);
    }
    hipLaunchKernelGGL(k_scatter, dim3(512), dim3(256), 0, stream, logit, stok, maskp, flag,
                       out, rowsum);
    hipLaunchKernelGGL(k_final, dim3(49, 256), dim3(256), 0, stream, out, rowsum);
}